// Round 10
// baseline (380.146 us; speedup 1.0000x reference)
//
#include <hip/hip_runtime.h>
#include <math.h>

typedef unsigned short u16;
typedef unsigned int   u32;
typedef _Float16 f16x8 __attribute__((ext_vector_type(8)));
typedef __attribute__((ext_vector_type(4))) float f32x4;

#define NB    4
#define IMGS  64
#define DSLAB (256*256)
#define TWO_PI 6.283185307179586f

// Scale plan (pipeline linear in pad; total compensated exactly in P4):
#define S_WX1  0.015625f
#define S_GMUL 0.015625f
#define S_P3   0.0625f
#define S_P4   (65536.0f / 88804.0f)

// ---------- fp16 2-way split ----------
__device__ __forceinline__ void split2(float x, u16& h, u16& l) {
  _Float16 hh = (_Float16)x;
  float r = x - (float)hh;
  _Float16 ll = (_Float16)r;
  h = *(u16*)&hh; l = *(u16*)&ll;
}
__device__ __forceinline__ u16 f2h(float x) {
  _Float16 hh = (_Float16)x;
  return *(u16*)&hh;
}

// ---------- async global->LDS 16B DMA ----------
__device__ __forceinline__ void gload16(const u16* g, u16* l) {
  __builtin_amdgcn_global_load_lds(
      (__attribute__((address_space(1))) void*)(g),
      (__attribute__((address_space(3))) void*)(l),
      16, 0, 0);
}

// ---------- fused static tables: tw, Wx1, We, B4t in ONE launch ----------
__global__ __launch_bounds__(256) void tables_k(float2* __restrict__ tw,
                                                u16* __restrict__ Wx1,
                                                u16* __restrict__ We,
                                                u16* __restrict__ B4t) {
  int idx = blockIdx.x * 256 + threadIdx.x;
  if (idx < 298) {
    float ang = (-TWO_PI / 298.0f) * (float)idx;
    float s, c; sincosf(ang, &s, &c);
    tw[idx] = make_float2(c, s);
  }
  if (idx < 122880) {   // Wx1 [2][384][320]
    int rho = idx / 320, n = idx % 320;
    float val = 0.f;
    if (rho < 300 && n < 298) {
      int v = rho >> 1, s = rho & 1;
      int m = (v * n) % 298;
      float ph = (TWO_PI / 298.0f) * (float)m;
      float sn, cs; sincosf(ph, &sn, &cs);
      val = (s ? sn : cs) * S_WX1;
    }
    u16 h, l; split2(val, h, l);
    Wx1[idx] = h; Wx1[122880 + idx] = l;
  }
  if (idx < 409600) {   // We [2][640][640]
    int j2 = idx / 640, k = idx % 640;
    int u = j2 >> 1, pc = j2 & 1;
    int mm = k >> 1, p = k & 1;
    float val = 0.f;
    if (u < 298 && mm < 298) {
      int m = (u * mm) % 298;
      float ph = (TWO_PI / 298.0f) * (float)m;
      float sn, cs; sincosf(ph, &sn, &cs);
      val = (pc == 0) ? (p == 0 ? cs : -sn) : (p == 0 ? -sn : -cs);
    }
    u16 h, l; split2(val, h, l);
    We[idx] = h; We[409600 + idx] = l;
  }
  if (idx < 40960) {    // B4t [1][256][320]
    int v = idx / 256, n = idx % 256;
    float re = 0.f, im = 0.f;
    if (v < 150) {
      int m = (v * (n + 21)) % 298;
      float ang = (-TWO_PI / 298.0f) * (float)m;
      float s, c; sincosf(ang, &s, &c);
      float fac = (v >= 1 && v < 149) ? 2.f : 1.f;
      re = fac * c; im = fac * s;
    }
    size_t o = (size_t)n * 320 + 2 * v;
    B4t[o] = f2h(re); B4t[o + 1] = f2h(im);
  }
}

// ---------- 1x1 reduce conv ----------
__global__ __launch_bounds__(256) void reduce_k(const float* __restrict__ x,
                                                const float* __restrict__ w,
                                                const float* __restrict__ bias,
                                                float* __restrict__ cls) {
  __shared__ float ws_[1024];
  __shared__ float bs_[16];
  int t = threadIdx.x;
  for (int i = t; i < 1024; i += 256) ws_[i] = w[i];
  if (t < 16) bs_[t] = bias[t];
  __syncthreads();
  int b = blockIdx.y;
  int hw = blockIdx.x * 256 + t;
  const float* xb = x + ((size_t)b * 64) * 65536 + hw;
  float acc[16];
#pragma unroll
  for (int c = 0; c < 16; c++) acc[c] = bs_[c];
  for (int k = 0; k < 64; k++) {
    float xv = xb[(size_t)k * 65536];
#pragma unroll
    for (int c = 0; c < 16; c++) acc[c] = fmaf(ws_[c * 64 + k], xv, acc[c]);
  }
  float* ob = cls + ((size_t)b * 16) * 65536 + hw;
#pragma unroll
  for (int c = 0; c < 16; c++) ob[(size_t)c * 65536] = acc[c];
}

// ---------- 3x3 VALID conv ----------
__global__ __launch_bounds__(256) void conv3_k(const float* __restrict__ in,
                                               const float* __restrict__ w,
                                               const float* __restrict__ bias,
                                               float* __restrict__ out,
                                               int HI, int WI, int relu) {
  __shared__ float ws_[2304];
  __shared__ float bs_[16];
  int t = threadIdx.x;
  for (int i = t; i < 2304; i += 256) ws_[i] = w[i];
  if (t < 16) bs_[t] = bias[t];
  __syncthreads();
  int HO = HI - 2, WO = WI - 2;
  int b = blockIdx.y;
  int idx = blockIdx.x * 256 + t;
  if (idx >= HO * WO) return;
  int y = idx / WO, xx = idx % WO;
  const float* ib = in + ((size_t)b * 16) * (size_t)(HI * WI);
  float acc[16];
#pragma unroll
  for (int c = 0; c < 16; c++) acc[c] = bs_[c];
  for (int ci = 0; ci < 16; ci++) {
    const float* p = ib + (size_t)ci * (HI * WI) + (size_t)y * WI + xx;
#pragma unroll
    for (int dy = 0; dy < 3; dy++) {
#pragma unroll
      for (int dx = 0; dx < 3; dx++) {
        float v = p[dy * WI + dx];
        int widx = ci * 9 + dy * 3 + dx;
#pragma unroll
        for (int co = 0; co < 16; co++)
          acc[co] = fmaf(ws_[co * 144 + widx], v, acc[co]);
      }
    }
  }
  float* ob = out + ((size_t)b * 16) * (size_t)(HO * WO) + (size_t)y * WO + xx;
#pragma unroll
  for (int co = 0; co < 16; co++) {
    float v = acc[co];
    if (relu) v = v > 0.f ? v : 0.1f * v;
    ob[(size_t)co * (HO * WO)] = v;
  }
}

// ---------- adaptive avg pool 250x250 -> 3x3 ----------
__global__ __launch_bounds__(256) void pool_k(const float* __restrict__ g,
                                              float* __restrict__ poolo) {
  int blk = blockIdx.x;
  int bc = blk / 9;
  int ij = blk % 9;
  int i = ij / 3, j = ij % 3;
  const int r0s[3] = {0, 83, 166}, r1s[3] = {84, 167, 250};
  int r0 = r0s[i], r1 = r1s[i], c0 = r0s[j], c1 = r1s[j];
  const float* p = g + (size_t)bc * 62500;
  int nc = c1 - c0;
  int tot = (r1 - r0) * nc;
  float s = 0.f;
  for (int e = threadIdx.x; e < tot; e += 256) {
    int rr = e / nc, cc = e % nc;
    s += p[(r0 + rr) * 250 + c0 + cc];
  }
  for (int off = 32; off > 0; off >>= 1) s += __shfl_down(s, off, 64);
  __shared__ float red[4];
  int lane = threadIdx.x & 63, wid = threadIdx.x >> 6;
  if (lane == 0) red[wid] = s;
  __syncthreads();
  if (threadIdx.x == 0) poolo[blk] = (red[0] + red[1] + red[2] + red[3]) / (float)tot;
}

// ---------- kernel_P ----------
__global__ __launch_bounds__(256) void kp_k(const float* __restrict__ poolv,
                                            const float* __restrict__ w4,
                                            const float* __restrict__ b4,
                                            float* __restrict__ kp) {
  int b = blockIdx.x;
  int t = threadIdx.x;
  __shared__ float vals[144];
  __shared__ float w_[256];
  __shared__ float bb[16];
  if (t < 256) w_[t] = w4[t];
  if (t < 16) bb[t] = b4[t];
  __syncthreads();
  if (t < 144) {
    int c = t / 9, ij = t % 9;
    float a = bb[c];
    for (int k = 0; k < 16; k++)
      a = fmaf(w_[c * 16 + k], poolv[b * 144 + k * 9 + ij], a);
    vals[t] = expf(a);
  }
  __syncthreads();
  if (t < 144) {
    int c = t / 9;
    float m = 0.f;
#pragma unroll
    for (int q = 0; q < 9; q++) m += vals[c * 9 + q];
    kp[b * 144 + t] = vals[t] - m * (1.0f / 9.0f);
  }
}

// ---------- pad (edge) + split2 into [2][64][384][320] fp16 ----------
__global__ __launch_bounds__(256) void padsplit_k(const float* __restrict__ cls,
                                                  u16* __restrict__ p0) {
  size_t idx = (size_t)blockIdx.x * 256 + threadIdx.x;
  if (idx >= 7864320u) return;
  int n = (int)(idx % 320);
  size_t rest = idx / 320;
  int m = (int)(rest % 384);
  size_t img = rest / 384;
  float val = 0.f;
  if (m < 298 && n < 298) {
    int sy = min(max(m - 21, 0), 255);
    int sx = min(max(n - 21, 0), 255);
    val = cls[img * 65536 + (size_t)sy * 256 + sx];
  }
  u16 h, l; split2(val, h, l);
  p0[idx] = h;
  p0[7864320u + idx] = l;
}

// ---------- Kf (half-plane v<150) ----------
__global__ __launch_bounds__(256) void kf_k(const float* __restrict__ ker,
                                            const float2* __restrict__ tw,
                                            float2* __restrict__ Kf) {
  int b = blockIdx.y;
  __shared__ float ks[441];
  int t = threadIdx.x;
  for (int i = t; i < 441; i += 256) ks[i] = ker[b * 441 + i];
  __syncthreads();
  int uv = blockIdx.x * 256 + t;
  if (uv >= 298 * 150) return;
  int u = uv / 150, v = uv % 150;
  int tu = (10 * u) % 298, tv = (10 * v) % 298;
  int t_i = (2 * 298 - tu - tv) % 298;
  float ar = 0.f, ai = 0.f;
  for (int i = 0; i < 21; i++) {
    int tt = t_i;
#pragma unroll
    for (int j = 0; j < 21; j++) {
      float kv = ks[i * 21 + j];
      float2 wv = tw[tt];
      ar = fmaf(kv, wv.x, ar);
      ai = fmaf(kv, wv.y, ai);
      tt += v; if (tt >= 298) tt -= 298;
    }
    t_i += u; if (t_i >= 298) t_i -= 298;
  }
  Kf[(size_t)b * (298 * 150) + uv] = make_float2(ar, ai);
}

// ---------- Wiener on Gt[v][u] fp32 -> Ge [1][64][384][640] fp16 expanded ----
__global__ __launch_bounds__(256) void gmul_k(const float* __restrict__ Gt,
                                              const float2* __restrict__ Kf,
                                              const float* __restrict__ kp,
                                              const float2* __restrict__ tw,
                                              u32* __restrict__ Geu) {
  int img = blockIdx.y;
  int b = img >> 4;
  __shared__ float kps[9];
  if (threadIdx.x < 9) kps[threadIdx.x] = kp[img * 9 + threadIdx.x];
  __syncthreads();
  int idx = blockIdx.x * 256 + threadIdx.x;
  if (idx >= 192 * 320) return;
  int u = idx % 320, v = idx / 320;
  float gr = 0.f, gi = 0.f;
  if (v < 150 && u < 298) {
    const float* gp = Gt + (size_t)img * 102400 + (size_t)v * 640 + 2 * u;
    float fr = gp[0], fi = gp[1];
    int um = (u == 0) ? 0 : (298 - u);
    int vm = (v == 0) ? 0 : (298 - v);
    int iu[3] = {um, 0, u}, jv[3] = {vm, 0, v};
    float pr = 0.f, pi = 0.f;
#pragma unroll
    for (int i = 0; i < 3; i++) {
#pragma unroll
      for (int j = 0; j < 3; j++) {
        int tt = iu[i] + jv[j];
        if (tt >= 298) tt -= 298;
        float kv = kps[i * 3 + j];
        float2 wv = tw[tt];
        pr = fmaf(kv, wv.x, pr);
        pi = fmaf(kv, wv.y, pi);
      }
    }
    float2 kf = Kf[(size_t)b * 44700 + (size_t)u * 150 + v];
    float denom = kf.x * kf.x + kf.y * kf.y + pr * pr + pi * pi;
    float inv = 1.0f / denom;
    float ir = kf.x * inv, ii = -kf.y * inv;
    gr = (ir * fr - ii * fi) * S_GMUL;
    gi = (ir * fi + ii * fr) * S_GMUL;
  }
  u16 ghr = f2h(gr), ghi = f2h(gi);
  size_t base = (size_t)img * 122880 + (size_t)(2 * v) * 320 + u;
  Geu[base]       = (u32)ghr | ((u32)ghi << 16);               // row 2v: ( r,  i)
  Geu[base + 320] = (u32)ghi | ((u32)(ghr ^ 0x8000u) << 16);   // row 2v+1: ( i, -r)
}

// ---------- staging helper (one K-tile, one buffer) ----------
template <int V, int PL>
__device__ __forceinline__ void stageT(const u16* __restrict__ Asrc,
                                       const u16* __restrict__ Bsrc,
                                       u16* Lb, int img, int m0, int n0,
                                       int kt, int w, int rof, int sub) {
  const int kb = kt * 64;
  u16* Al = Lb;
  u16* Bl = Lb + PL * 8192;
#pragma unroll
  for (int i = 0; i < PL * 4; ++i) {
    int q = w + i * 4;
    int p = (PL == 2) ? (q >> 4) : 0;
    int j = (PL == 2) ? (q & 15) : q;
    int r = j * 8 + rof;
    const u16* ga;
    if constexpr (V == 1) {
      ga = Asrc + (size_t)p * 122880u + (size_t)(m0 + r) * 320 + kb + sub * 8;
    } else if constexpr (V == 2) {
      int gr = m0 + r; if (gr > 191) gr = 191;
      ga = Asrc + (size_t)p * 7864320u + (size_t)img * 122880u +
           (size_t)gr * 640 + kb + sub * 8;
    } else if constexpr (V == 3) {
      ga = Asrc + (size_t)(2 * (m0 + r + 21)) * 640 + kb + sub * 8;
    } else {
      ga = Asrc + (size_t)img * 81920u + (size_t)(m0 + r) * 320 + kb + sub * 8;
    }
    gload16(ga, Al + q * 512);
  }
#pragma unroll
  for (int i = 0; i < PL * 4; ++i) {
    int q = w + i * 4;
    int p = (PL == 2) ? (q >> 4) : 0;
    int j = (PL == 2) ? (q & 15) : q;
    int rr = j * 8 + rof;
    const u16* gb;
    if constexpr (V == 1) {
      gb = Bsrc + (size_t)p * 7864320u + (size_t)img * 122880u +
           (size_t)(n0 + rr) * 320 + kb + sub * 8;
    } else if constexpr (V == 2) {
      gb = Bsrc + (size_t)p * 409600u + (size_t)(n0 + rr) * 640 + kb + sub * 8;
    } else if constexpr (V == 3) {
      gb = Bsrc + (size_t)img * 245760u + (size_t)(n0 + rr) * 640 + kb + sub * 8;
    } else {
      gb = Bsrc + (size_t)(n0 + rr) * 320 + kb + sub * 8;
    }
    gload16(gb, Bl + q * 512);
  }
}

// ---------- fp16-split MFMA GEMM: dbuf LDS + counted vmcnt + XCD swizzle ----
// BM=BN=128, BK=64, 4 waves (2x2), wave tile 64x64; XOR slot swizzle (2-way).
// 1D grid (nwg % 8 == 0); bijective XCD remap keeps same-image blocks on one XCD.
template <int V>
__global__ __launch_bounds__(256) void gemmF(
    const u16* __restrict__ Asrc, const u16* __restrict__ Bsrc,
    float* __restrict__ oF, u16* __restrict__ o0,
    int nbn, int npi, int KT) {
  constexpr int PL = (V <= 2) ? 2 : 1;
  constexpr int BUF = PL * 2 * 8192;   // u16 per buffer
  __shared__ u16 lds[2 * BUF];
  const int tid = threadIdx.x;
  const int nwg = gridDim.x;
  const int wg = blockIdx.x;
  const int vid = (wg & 7) * (nwg >> 3) + (wg >> 3);
  const int img = vid / npi;
  const int rem = vid % npi;
  const int m0 = (rem / nbn) * 128;
  const int n0 = (rem % nbn) * 128;
  const int l = tid & 63;
  const int w = tid >> 6;
  const int wm = w & 1, wn = w >> 1;
  const int rof = l >> 3;
  const int sub = (l & 7) ^ rof;
  const int arow = wm * 64 + (l & 15);
  const int brow = wn * 64 + (l & 15);

  f32x4 acc[4][4];
#pragma unroll
  for (int i = 0; i < 4; i++)
#pragma unroll
    for (int j = 0; j < 4; j++) acc[i][j] = (f32x4){0.f, 0.f, 0.f, 0.f};

  stageT<V, PL>(Asrc, Bsrc, lds, img, m0, n0, 0, w, rof, sub);
  int c = 0;
  for (int kt = 0; kt < KT; ++kt) {
    if (kt + 1 < KT) {
      stageT<V, PL>(Asrc, Bsrc, lds + (c ^ 1) * BUF, img, m0, n0, kt + 1, w, rof, sub);
      asm volatile("s_waitcnt vmcnt(%0)" :: "n"(PL * 8) : "memory");
    } else {
      asm volatile("s_waitcnt vmcnt(0)" ::: "memory");
    }
    __builtin_amdgcn_s_barrier();
    const u16* Al = lds + c * BUF;
    const u16* Bl = Al + PL * 8192;
#pragma unroll
    for (int kk = 0; kk < 2; ++kk) {
      const int slot = ((kk * 4 + (l >> 4)) ^ (l & 7)) * 8;
      f16x8 af[4][PL], bf[4][PL];
#pragma unroll
      for (int fm = 0; fm < 4; ++fm)
#pragma unroll
        for (int p = 0; p < PL; ++p)
          af[fm][p] = *(const f16x8*)&Al[p * 8192 + (arow + fm * 16) * 64 + slot];
#pragma unroll
      for (int fn = 0; fn < 4; ++fn)
#pragma unroll
        for (int p = 0; p < PL; ++p)
          bf[fn][p] = *(const f16x8*)&Bl[p * 8192 + (brow + fn * 16) * 64 + slot];
#pragma unroll
      for (int fm = 0; fm < 4; ++fm)
#pragma unroll
        for (int fn = 0; fn < 4; ++fn) {
          f32x4 a = acc[fm][fn];
          if constexpr (PL == 2) {
            a = __builtin_amdgcn_mfma_f32_16x16x32_f16(af[fm][1], bf[fn][0], a, 0, 0, 0);
            a = __builtin_amdgcn_mfma_f32_16x16x32_f16(af[fm][0], bf[fn][1], a, 0, 0, 0);
            a = __builtin_amdgcn_mfma_f32_16x16x32_f16(af[fm][0], bf[fn][0], a, 0, 0, 0);
          } else {
            a = __builtin_amdgcn_mfma_f32_16x16x32_f16(af[fm][0], bf[fn][0], a, 0, 0, 0);
          }
          acc[fm][fn] = a;
        }
    }
    asm volatile("" ::: "memory");
    __builtin_amdgcn_s_barrier();
    c ^= 1;
  }

  // ---- epilogue ----
  const int rowL = (l >> 4) * 4;
  const int colL = l & 15;
#pragma unroll
  for (int fm = 0; fm < 4; ++fm)
#pragma unroll
    for (int fn = 0; fn < 4; ++fn) {
      int gcol = n0 + wn * 64 + fn * 16 + colL;
      int rbase = m0 + wm * 64 + fm * 16 + rowL;
      if constexpr (V == 1) {
        if (gcol < 320) {
          u32* T1u = (u32*)o0;
#pragma unroll
          for (int i = 0; i < 4; i += 2) {
            int rho = rbase + i;
            int v = rho >> 1;
            u16 h0, l0, h1, l1;
            split2(acc[fm][fn][i], h0, l0);
            split2(acc[fm][fn][i + 1], h1, l1);
            size_t off = (size_t)img * 61440u + (size_t)v * 320 + gcol;
            T1u[off] = (u32)h0 | ((u32)h1 << 16);
            T1u[3932160u + off] = (u32)l0 | ((u32)l1 << 16);
          }
        }
      } else if constexpr (V == 2) {
#pragma unroll
        for (int i = 0; i < 4; ++i) {
          int vg = rbase + i;
          if (vg < 160)
            oF[(size_t)img * 102400u + (size_t)vg * 640 + gcol] = acc[fm][fn][i];
        }
      } else if constexpr (V == 3) {
        if (gcol < 320) {
#pragma unroll
          for (int i = 0; i < 4; ++i) {
            int mg = rbase + i;
            size_t off = (size_t)img * 81920u + (size_t)mg * 320 + gcol;
            o0[off] = f2h(acc[fm][fn][i] * S_P3);
          }
        }
      } else {
#pragma unroll
        for (int i = 0; i < 4; ++i) {
          int mg = rbase + i;
          oF[(size_t)img * 65536u + (size_t)mg * 256 + gcol] = acc[fm][fn][i] * S_P4;
        }
      }
    }
}

// ---------- 1x1 expand conv ----------
__global__ __launch_bounds__(256) void expand_k(const float* __restrict__ D,
                                                const float* __restrict__ w,
                                                const float* __restrict__ bias,
                                                float* __restrict__ out) {
  __shared__ float ws_[1024];
  __shared__ float bs_[64];
  int t = threadIdx.x;
  for (int i = t; i < 1024; i += 256) ws_[i] = w[i];
  if (t < 64) bs_[t] = bias[t];
  __syncthreads();
  int b = blockIdx.y;
  int hw = blockIdx.x * 256 + t;
  const float* Db = D + (size_t)b * 16 * DSLAB + hw;
  float d[16];
#pragma unroll
  for (int c = 0; c < 16; c++) d[c] = Db[(size_t)c * DSLAB];
  float* ob = out + ((size_t)b * 64) * 65536 + hw;
  for (int o = 0; o < 64; o++) {
    float a = bs_[o];
#pragma unroll
    for (int c = 0; c < 16; c++) a = fmaf(ws_[o * 16 + c], d[c], a);
    ob[(size_t)o * 65536] = a;
  }
}

extern "C" void kernel_launch(void* const* d_in, const int* in_sizes, int n_in,
                              void* d_out, int out_size, void* d_ws, size_t ws_size,
                              hipStream_t stream) {
  (void)in_sizes; (void)n_in; (void)out_size; (void)ws_size;
  const float* x        = (const float*)d_in[0];
  const float* kernel   = (const float*)d_in[1];
  const float* w_reduce = (const float*)d_in[2];
  const float* b_reduce = (const float*)d_in[3];
  const float* w_g1     = (const float*)d_in[4];
  const float* b_g1     = (const float*)d_in[5];
  const float* w_g2     = (const float*)d_in[6];
  const float* b_g2     = (const float*)d_in[7];
  const float* w_g3     = (const float*)d_in[8];
  const float* b_g3     = (const float*)d_in[9];
  const float* w_g4     = (const float*)d_in[10];
  const float* b_g4     = (const float*)d_in[11];
  const float* w_expand = (const float*)d_in[12];
  const float* b_expand = (const float*)d_in[13];
  float* out = (float*)d_out;

  // ---- workspace layout (float offsets); all aliases time-disjoint ----
  float* ws_f = (float*)d_ws;
  float* cls   = ws_f;
  float* gA    = ws_f + 4194304;
  float* gB    = ws_f + 8323328;
  u16*  padsp  = (u16*)(ws_f + 4194304);
  u16*  T1e    = (u16*)(ws_f + 12452352);
  float* Gt    = ws_f;
  u16*  Ge     = (u16*)(ws_f + 12452352);
  u16*  E2     = (u16*)ws_f;
  float* Df    = ws_f + 5242880;
  float2* tw   = (float2*)(ws_f + 28180992);
  float2* Kf2  = (float2*)(ws_f + 28182016);
  u16*  Wx1    = (u16*)(ws_f + 28540416);
  u16*  We     = (u16*)(ws_f + 28663296);
  u16*  B4t    = (u16*)(ws_f + 29072896);
  float* poolb = ws_f + 29154816;
  float* kpb   = ws_f + 29155392;

  // ---- static tables (single fused launch) ----
  tables_k<<<dim3(1600), 256, 0, stream>>>(tw, Wx1, We, B4t);

  // ---- conv chain ----
  reduce_k<<<dim3(256, NB), 256, 0, stream>>>(x, w_reduce, b_reduce, cls);
  conv3_k<<<dim3((254 * 254 + 255) / 256, NB), 256, 0, stream>>>(cls, w_g1, b_g1, gA, 256, 256, 1);
  conv3_k<<<dim3((252 * 252 + 255) / 256, NB), 256, 0, stream>>>(gA, w_g2, b_g2, gB, 254, 254, 1);
  conv3_k<<<dim3((250 * 250 + 255) / 256, NB), 256, 0, stream>>>(gB, w_g3, b_g3, gA, 252, 252, 0);
  pool_k<<<dim3(NB * 16 * 9), 256, 0, stream>>>(gA, poolb);
  kp_k<<<dim3(NB), 256, 0, stream>>>(poolb, w_g4, b_g4, kpb);

  // ---- pad + split, Kf ----
  padsplit_k<<<dim3(30720), 256, 0, stream>>>(cls, padsp);
  kf_k<<<dim3((298 * 150 + 255) / 256, NB), 256, 0, stream>>>(kernel, tw, Kf2);

  // ---- P1: T1e = Wx1 x pad^T  (2-plane, 3-product; 576 blocks) ----
  gemmF<1><<<dim3(576), 256, 0, stream>>>(Wx1, padsp, nullptr, T1e, 3, 9, 5);
  // ---- P2: Gt = T1e x We^T  (2-plane, 3-product; 640 blocks) ----
  gemmF<2><<<dim3(640), 256, 0, stream>>>(T1e, We, Gt, nullptr, 5, 10, 10);
  // ---- Wiener + expand -> Ge (single plane, scaled 1/64) ----
  gmul_k<<<dim3(240, IMGS), 256, 0, stream>>>(Gt, Kf2, kpb, tw, (u32*)Ge);
  // ---- P3: E = We(rows 2(m+21)) x Ge^T  (1-plane; 384 blocks) ----
  gemmF<3><<<dim3(384), 256, 0, stream>>>(We, Ge, nullptr, E2, 3, 6, 10);
  // ---- P4: D = E2 x B4t^T  (1-plane; 256 blocks) ----
  gemmF<4><<<dim3(256), 256, 0, stream>>>(E2, B4t, Df, nullptr, 2, 4, 5);
  // ---- expand ----
  expand_k<<<dim3(256, NB), 256, 0, stream>>>(Df, w_expand, b_expand, out);
}

// Round 11
// 378.705 us; speedup vs baseline: 1.0038x; 1.0038x over previous
//
#include <hip/hip_runtime.h>
#include <math.h>

typedef unsigned short u16;
typedef unsigned int   u32;
typedef _Float16 f16x8 __attribute__((ext_vector_type(8)));
typedef __attribute__((ext_vector_type(4))) float f32x4;

#define NB    4
#define IMGS  64
#define DSLAB (256*256)
#define TWO_PI 6.283185307179586f

// Scale plan (pipeline linear in pad; total compensated exactly in P4):
#define S_WX1  0.015625f
#define S_GMUL 0.015625f
#define S_P3   0.0625f
#define S_P4   (65536.0f / 88804.0f)

// ---------- fp16 2-way split ----------
__device__ __forceinline__ void split2(float x, u16& h, u16& l) {
  _Float16 hh = (_Float16)x;
  float r = x - (float)hh;
  _Float16 ll = (_Float16)r;
  h = *(u16*)&hh; l = *(u16*)&ll;
}
__device__ __forceinline__ u16 f2h(float x) {
  _Float16 hh = (_Float16)x;
  return *(u16*)&hh;
}

// ---------- async global->LDS 16B DMA ----------
__device__ __forceinline__ void gload16(const u16* g, u16* l) {
  __builtin_amdgcn_global_load_lds(
      (__attribute__((address_space(1))) void*)(g),
      (__attribute__((address_space(3))) void*)(l),
      16, 0, 0);
}

// ---------- fused static tables: tw, Wx1, We, B4t in ONE launch ----------
__global__ __launch_bounds__(256) void tables_k(float2* __restrict__ tw,
                                                u16* __restrict__ Wx1,
                                                u16* __restrict__ We,
                                                u16* __restrict__ B4t) {
  int idx = blockIdx.x * 256 + threadIdx.x;
  if (idx < 298) {
    float ang = (-TWO_PI / 298.0f) * (float)idx;
    float s, c; sincosf(ang, &s, &c);
    tw[idx] = make_float2(c, s);
  }
  if (idx < 122880) {   // Wx1 [2][384][320]
    int rho = idx / 320, n = idx % 320;
    float val = 0.f;
    if (rho < 300 && n < 298) {
      int v = rho >> 1, s = rho & 1;
      int m = (v * n) % 298;
      float ph = (TWO_PI / 298.0f) * (float)m;
      float sn, cs; sincosf(ph, &sn, &cs);
      val = (s ? sn : cs) * S_WX1;
    }
    u16 h, l; split2(val, h, l);
    Wx1[idx] = h; Wx1[122880 + idx] = l;
  }
  if (idx < 409600) {   // We [2][640][640]
    int j2 = idx / 640, k = idx % 640;
    int u = j2 >> 1, pc = j2 & 1;
    int mm = k >> 1, p = k & 1;
    float val = 0.f;
    if (u < 298 && mm < 298) {
      int m = (u * mm) % 298;
      float ph = (TWO_PI / 298.0f) * (float)m;
      float sn, cs; sincosf(ph, &sn, &cs);
      val = (pc == 0) ? (p == 0 ? cs : -sn) : (p == 0 ? -sn : -cs);
    }
    u16 h, l; split2(val, h, l);
    We[idx] = h; We[409600 + idx] = l;
  }
  if (idx < 40960) {    // B4t [1][256][320]
    int v = idx / 256, n = idx % 256;
    float re = 0.f, im = 0.f;
    if (v < 150) {
      int m = (v * (n + 21)) % 298;
      float ang = (-TWO_PI / 298.0f) * (float)m;
      float s, c; sincosf(ang, &s, &c);
      float fac = (v >= 1 && v < 149) ? 2.f : 1.f;
      re = fac * c; im = fac * s;
    }
    size_t o = (size_t)n * 320 + 2 * v;
    B4t[o] = f2h(re); B4t[o + 1] = f2h(im);
  }
}

// ---------- 1x1 reduce conv via MFMA (fp16 2-split, 3 products) ----------
// cls[16oc][px] = W[16][64] x x[64][px] + b.  B-frags assembled from global
// with per-lane scalar loads (native [k][n] layout), split in-register.
__global__ __launch_bounds__(256) void reduce_mfma_k(const float* __restrict__ x,
                                                     const float* __restrict__ w,
                                                     const float* __restrict__ bias,
                                                     float* __restrict__ cls) {
  __shared__ u16 Wp[2 * 1024];
  __shared__ float bs[16];
  int t = threadIdx.x;
  for (int i = t; i < 1024; i += 256) {
    u16 h, l; split2(w[i], h, l);
    Wp[i] = h; Wp[1024 + i] = l;
  }
  if (t < 16) bs[t] = bias[t];
  __syncthreads();
  const int b = blockIdx.x >> 8;
  const int px0 = (blockIdx.x & 255) * 256;
  const int l = t & 63, wv = t >> 6;
  const int pxb = px0 + wv * 64;
  const int kgrp = l >> 4;
  f16x8 af[2][2];
#pragma unroll
  for (int kt = 0; kt < 2; ++kt)
#pragma unroll
    for (int p = 0; p < 2; ++p)
      af[kt][p] = *(const f16x8*)&Wp[p * 1024 + (l & 15) * 64 + kt * 32 + kgrp * 8];
  const float* xb = x + (size_t)b * 64 * 65536;
  float xv[2][4][8];
#pragma unroll
  for (int kt = 0; kt < 2; ++kt)
#pragma unroll
    for (int pxf = 0; pxf < 4; ++pxf) {
      int px = pxb + pxf * 16 + (l & 15);
      const float* p0 = xb + (size_t)(kt * 32 + kgrp * 8) * 65536 + px;
#pragma unroll
      for (int j = 0; j < 8; ++j) xv[kt][pxf][j] = p0[(size_t)j * 65536];
    }
  f32x4 acc[4];
#pragma unroll
  for (int i = 0; i < 4; ++i) acc[i] = (f32x4){0.f, 0.f, 0.f, 0.f};
#pragma unroll
  for (int kt = 0; kt < 2; ++kt)
#pragma unroll
    for (int pxf = 0; pxf < 4; ++pxf) {
      f16x8 bh, bl;
#pragma unroll
      for (int j = 0; j < 8; ++j) {
        float v = xv[kt][pxf][j];
        _Float16 hh = (_Float16)v;
        _Float16 ll = (_Float16)(v - (float)hh);
        bh[j] = hh; bl[j] = ll;
      }
      f32x4 a = acc[pxf];
      a = __builtin_amdgcn_mfma_f32_16x16x32_f16(af[kt][0], bl, a, 0, 0, 0);
      a = __builtin_amdgcn_mfma_f32_16x16x32_f16(af[kt][1], bh, a, 0, 0, 0);
      a = __builtin_amdgcn_mfma_f32_16x16x32_f16(af[kt][0], bh, a, 0, 0, 0);
      acc[pxf] = a;
    }
  float* ob = cls + (size_t)b * 16 * 65536;
#pragma unroll
  for (int pxf = 0; pxf < 4; ++pxf) {
    int px = pxb + pxf * 16 + (l & 15);
#pragma unroll
    for (int i = 0; i < 4; ++i) {
      int oc = kgrp * 4 + i;
      ob[(size_t)oc * 65536 + px] = acc[pxf][i] + bs[oc];
    }
  }
}

// ---------- 1x1 expand conv via MFMA (K padded 16->32, D fp16 planes) -------
__global__ __launch_bounds__(256) void expand_mfma_k(const u16* __restrict__ Dh,
                                                     const float* __restrict__ w,
                                                     const float* __restrict__ bias,
                                                     float* __restrict__ out) {
  __shared__ u16 Wp[2 * 2048];
  __shared__ float bs[64];
  int t = threadIdx.x;
  for (int i = t; i < 2048; i += 256) {
    int oc = i >> 5, k = i & 31;
    float v = (k < 16) ? w[oc * 16 + k] : 0.f;
    u16 h, l; split2(v, h, l);
    Wp[i] = h; Wp[2048 + i] = l;
  }
  if (t < 64) bs[t] = bias[t];
  __syncthreads();
  const int b = blockIdx.x >> 8;
  const int px0 = (blockIdx.x & 255) * 256;
  const int l = t & 63, wv = t >> 6;
  const int pxb = px0 + wv * 64;
  const int kgrp = l >> 4;
  f16x8 af[4][2];
#pragma unroll
  for (int mf = 0; mf < 4; ++mf)
#pragma unroll
    for (int p = 0; p < 2; ++p)
      af[mf][p] = *(const f16x8*)&Wp[p * 2048 + (mf * 16 + (l & 15)) * 32 + kgrp * 8];
  const int chb = kgrp * 8;             // k 0..31; rows >=16 are zero padding
  f32x4 acc[4][4];
#pragma unroll
  for (int i = 0; i < 4; ++i)
#pragma unroll
    for (int j = 0; j < 4; ++j) acc[i][j] = (f32x4){0.f, 0.f, 0.f, 0.f};
#pragma unroll
  for (int pxf = 0; pxf < 4; ++pxf) {
    int px = pxb + pxf * 16 + (l & 15);
    f16x8 bh, bl;
#pragma unroll
    for (int j = 0; j < 8; ++j) {
      _Float16 hv = (_Float16)0.f, lv = (_Float16)0.f;
      if (chb < 16) {
        size_t off = (size_t)(b * 16 + chb + j) * 65536 + px;
        hv = *(const _Float16*)&Dh[off];
        lv = *(const _Float16*)&Dh[4194304u + off];
      }
      bh[j] = hv; bl[j] = lv;
    }
#pragma unroll
    for (int mf = 0; mf < 4; ++mf) {
      f32x4 a = acc[pxf][mf];
      a = __builtin_amdgcn_mfma_f32_16x16x32_f16(af[mf][0], bl, a, 0, 0, 0);
      a = __builtin_amdgcn_mfma_f32_16x16x32_f16(af[mf][1], bh, a, 0, 0, 0);
      a = __builtin_amdgcn_mfma_f32_16x16x32_f16(af[mf][0], bh, a, 0, 0, 0);
      acc[pxf][mf] = a;
    }
  }
  float* ob = out + (size_t)b * 64 * 65536;
#pragma unroll
  for (int pxf = 0; pxf < 4; ++pxf) {
    int px = pxb + pxf * 16 + (l & 15);
#pragma unroll
    for (int mf = 0; mf < 4; ++mf)
#pragma unroll
      for (int i = 0; i < 4; ++i) {
        int oc = mf * 16 + kgrp * 4 + i;
        ob[(size_t)oc * 65536 + px] = acc[pxf][mf][i] + bs[oc];
      }
  }
}

// ---------- 3x3 VALID conv ----------
__global__ __launch_bounds__(256) void conv3_k(const float* __restrict__ in,
                                               const float* __restrict__ w,
                                               const float* __restrict__ bias,
                                               float* __restrict__ out,
                                               int HI, int WI, int relu) {
  __shared__ float ws_[2304];
  __shared__ float bs_[16];
  int t = threadIdx.x;
  for (int i = t; i < 2304; i += 256) ws_[i] = w[i];
  if (t < 16) bs_[t] = bias[t];
  __syncthreads();
  int HO = HI - 2, WO = WI - 2;
  int b = blockIdx.y;
  int idx = blockIdx.x * 256 + t;
  if (idx >= HO * WO) return;
  int y = idx / WO, xx = idx % WO;
  const float* ib = in + ((size_t)b * 16) * (size_t)(HI * WI);
  float acc[16];
#pragma unroll
  for (int c = 0; c < 16; c++) acc[c] = bs_[c];
  for (int ci = 0; ci < 16; ci++) {
    const float* p = ib + (size_t)ci * (HI * WI) + (size_t)y * WI + xx;
#pragma unroll
    for (int dy = 0; dy < 3; dy++) {
#pragma unroll
      for (int dx = 0; dx < 3; dx++) {
        float v = p[dy * WI + dx];
        int widx = ci * 9 + dy * 3 + dx;
#pragma unroll
        for (int co = 0; co < 16; co++)
          acc[co] = fmaf(ws_[co * 144 + widx], v, acc[co]);
      }
    }
  }
  float* ob = out + ((size_t)b * 16) * (size_t)(HO * WO) + (size_t)y * WO + xx;
#pragma unroll
  for (int co = 0; co < 16; co++) {
    float v = acc[co];
    if (relu) v = v > 0.f ? v : 0.1f * v;
    ob[(size_t)co * (HO * WO)] = v;
  }
}

// ---------- adaptive avg pool 250x250 -> 3x3 ----------
__global__ __launch_bounds__(256) void pool_k(const float* __restrict__ g,
                                              float* __restrict__ poolo) {
  int blk = blockIdx.x;
  int bc = blk / 9;
  int ij = blk % 9;
  int i = ij / 3, j = ij % 3;
  const int r0s[3] = {0, 83, 166}, r1s[3] = {84, 167, 250};
  int r0 = r0s[i], r1 = r1s[i], c0 = r0s[j], c1 = r1s[j];
  const float* p = g + (size_t)bc * 62500;
  int nc = c1 - c0;
  int tot = (r1 - r0) * nc;
  float s = 0.f;
  for (int e = threadIdx.x; e < tot; e += 256) {
    int rr = e / nc, cc = e % nc;
    s += p[(r0 + rr) * 250 + c0 + cc];
  }
  for (int off = 32; off > 0; off >>= 1) s += __shfl_down(s, off, 64);
  __shared__ float red[4];
  int lane = threadIdx.x & 63, wid = threadIdx.x >> 6;
  if (lane == 0) red[wid] = s;
  __syncthreads();
  if (threadIdx.x == 0) poolo[blk] = (red[0] + red[1] + red[2] + red[3]) / (float)tot;
}

// ---------- kernel_P ----------
__global__ __launch_bounds__(256) void kp_k(const float* __restrict__ poolv,
                                            const float* __restrict__ w4,
                                            const float* __restrict__ b4,
                                            float* __restrict__ kp) {
  int b = blockIdx.x;
  int t = threadIdx.x;
  __shared__ float vals[144];
  __shared__ float w_[256];
  __shared__ float bb[16];
  if (t < 256) w_[t] = w4[t];
  if (t < 16) bb[t] = b4[t];
  __syncthreads();
  if (t < 144) {
    int c = t / 9, ij = t % 9;
    float a = bb[c];
    for (int k = 0; k < 16; k++)
      a = fmaf(w_[c * 16 + k], poolv[b * 144 + k * 9 + ij], a);
    vals[t] = expf(a);
  }
  __syncthreads();
  if (t < 144) {
    int c = t / 9;
    float m = 0.f;
#pragma unroll
    for (int q = 0; q < 9; q++) m += vals[c * 9 + q];
    kp[b * 144 + t] = vals[t] - m * (1.0f / 9.0f);
  }
}

// ---------- pad (edge) + split2 into [2][64][384][320] fp16 ----------
__global__ __launch_bounds__(256) void padsplit_k(const float* __restrict__ cls,
                                                  u16* __restrict__ p0) {
  size_t idx = (size_t)blockIdx.x * 256 + threadIdx.x;
  if (idx >= 7864320u) return;
  int n = (int)(idx % 320);
  size_t rest = idx / 320;
  int m = (int)(rest % 384);
  size_t img = rest / 384;
  float val = 0.f;
  if (m < 298 && n < 298) {
    int sy = min(max(m - 21, 0), 255);
    int sx = min(max(n - 21, 0), 255);
    val = cls[img * 65536 + (size_t)sy * 256 + sx];
  }
  u16 h, l; split2(val, h, l);
  p0[idx] = h;
  p0[7864320u + idx] = l;
}

// ---------- Kf (half-plane v<150) ----------
__global__ __launch_bounds__(256) void kf_k(const float* __restrict__ ker,
                                            const float2* __restrict__ tw,
                                            float2* __restrict__ Kf) {
  int b = blockIdx.y;
  __shared__ float ks[441];
  int t = threadIdx.x;
  for (int i = t; i < 441; i += 256) ks[i] = ker[b * 441 + i];
  __syncthreads();
  int uv = blockIdx.x * 256 + t;
  if (uv >= 298 * 150) return;
  int u = uv / 150, v = uv % 150;
  int tu = (10 * u) % 298, tv = (10 * v) % 298;
  int t_i = (2 * 298 - tu - tv) % 298;
  float ar = 0.f, ai = 0.f;
  for (int i = 0; i < 21; i++) {
    int tt = t_i;
#pragma unroll
    for (int j = 0; j < 21; j++) {
      float kv = ks[i * 21 + j];
      float2 wv = tw[tt];
      ar = fmaf(kv, wv.x, ar);
      ai = fmaf(kv, wv.y, ai);
      tt += v; if (tt >= 298) tt -= 298;
    }
    t_i += u; if (t_i >= 298) t_i -= 298;
  }
  Kf[(size_t)b * (298 * 150) + uv] = make_float2(ar, ai);
}

// ---------- Wiener on Gt[v][u] fp32 -> Ge [1][64][384][640] fp16 expanded ----
__global__ __launch_bounds__(256) void gmul_k(const float* __restrict__ Gt,
                                              const float2* __restrict__ Kf,
                                              const float* __restrict__ kp,
                                              const float2* __restrict__ tw,
                                              u32* __restrict__ Geu) {
  int img = blockIdx.y;
  int b = img >> 4;
  __shared__ float kps[9];
  if (threadIdx.x < 9) kps[threadIdx.x] = kp[img * 9 + threadIdx.x];
  __syncthreads();
  int idx = blockIdx.x * 256 + threadIdx.x;
  if (idx >= 192 * 320) return;
  int u = idx % 320, v = idx / 320;
  float gr = 0.f, gi = 0.f;
  if (v < 150 && u < 298) {
    const float* gp = Gt + (size_t)img * 102400 + (size_t)v * 640 + 2 * u;
    float fr = gp[0], fi = gp[1];
    int um = (u == 0) ? 0 : (298 - u);
    int vm = (v == 0) ? 0 : (298 - v);
    int iu[3] = {um, 0, u}, jv[3] = {vm, 0, v};
    float pr = 0.f, pi = 0.f;
#pragma unroll
    for (int i = 0; i < 3; i++) {
#pragma unroll
      for (int j = 0; j < 3; j++) {
        int tt = iu[i] + jv[j];
        if (tt >= 298) tt -= 298;
        float kv = kps[i * 3 + j];
        float2 wv = tw[tt];
        pr = fmaf(kv, wv.x, pr);
        pi = fmaf(kv, wv.y, pi);
      }
    }
    float2 kf = Kf[(size_t)b * 44700 + (size_t)u * 150 + v];
    float denom = kf.x * kf.x + kf.y * kf.y + pr * pr + pi * pi;
    float inv = 1.0f / denom;
    float ir = kf.x * inv, ii = -kf.y * inv;
    gr = (ir * fr - ii * fi) * S_GMUL;
    gi = (ir * fi + ii * fr) * S_GMUL;
  }
  u16 ghr = f2h(gr), ghi = f2h(gi);
  size_t base = (size_t)img * 122880 + (size_t)(2 * v) * 320 + u;
  Geu[base]       = (u32)ghr | ((u32)ghi << 16);               // row 2v: ( r,  i)
  Geu[base + 320] = (u32)ghi | ((u32)(ghr ^ 0x8000u) << 16);   // row 2v+1: ( i, -r)
}

// ---------- staging helper (one K-tile, one buffer) ----------
template <int V, int PL>
__device__ __forceinline__ void stageT(const u16* __restrict__ Asrc,
                                       const u16* __restrict__ Bsrc,
                                       u16* Lb, int img, int m0, int n0,
                                       int kt, int w, int rof, int sub) {
  const int kb = kt * 64;
  u16* Al = Lb;
  u16* Bl = Lb + PL * 8192;
#pragma unroll
  for (int i = 0; i < PL * 4; ++i) {
    int q = w + i * 4;
    int p = (PL == 2) ? (q >> 4) : 0;
    int j = (PL == 2) ? (q & 15) : q;
    int r = j * 8 + rof;
    const u16* ga;
    if constexpr (V == 1) {
      ga = Asrc + (size_t)p * 122880u + (size_t)(m0 + r) * 320 + kb + sub * 8;
    } else if constexpr (V == 2) {
      int gr = m0 + r; if (gr > 191) gr = 191;
      ga = Asrc + (size_t)p * 7864320u + (size_t)img * 122880u +
           (size_t)gr * 640 + kb + sub * 8;
    } else if constexpr (V == 3) {
      ga = Asrc + (size_t)(2 * (m0 + r + 21)) * 640 + kb + sub * 8;
    } else {
      ga = Asrc + (size_t)img * 81920u + (size_t)(m0 + r) * 320 + kb + sub * 8;
    }
    gload16(ga, Al + q * 512);
  }
#pragma unroll
  for (int i = 0; i < PL * 4; ++i) {
    int q = w + i * 4;
    int p = (PL == 2) ? (q >> 4) : 0;
    int j = (PL == 2) ? (q & 15) : q;
    int rr = j * 8 + rof;
    const u16* gb;
    if constexpr (V == 1) {
      gb = Bsrc + (size_t)p * 7864320u + (size_t)img * 122880u +
           (size_t)(n0 + rr) * 320 + kb + sub * 8;
    } else if constexpr (V == 2) {
      gb = Bsrc + (size_t)p * 409600u + (size_t)(n0 + rr) * 640 + kb + sub * 8;
    } else if constexpr (V == 3) {
      gb = Bsrc + (size_t)img * 245760u + (size_t)(n0 + rr) * 640 + kb + sub * 8;
    } else {
      gb = Bsrc + (size_t)(n0 + rr) * 320 + kb + sub * 8;
    }
    gload16(gb, Bl + q * 512);
  }
}

// ---------- fp16-split MFMA GEMM: dbuf LDS + counted vmcnt + XCD swizzle ----
template <int V>
__global__ __launch_bounds__(256) void gemmF(
    const u16* __restrict__ Asrc, const u16* __restrict__ Bsrc,
    float* __restrict__ oF, u16* __restrict__ o0,
    int nbn, int npi, int KT) {
  constexpr int PL = (V <= 2) ? 2 : 1;
  constexpr int BUF = PL * 2 * 8192;   // u16 per buffer
  __shared__ u16 lds[2 * BUF];
  const int tid = threadIdx.x;
  const int nwg = gridDim.x;
  const int wg = blockIdx.x;
  const int vid = (wg & 7) * (nwg >> 3) + (wg >> 3);
  const int img = vid / npi;
  const int rem = vid % npi;
  const int m0 = (rem / nbn) * 128;
  const int n0 = (rem % nbn) * 128;
  const int l = tid & 63;
  const int w = tid >> 6;
  const int wm = w & 1, wn = w >> 1;
  const int rof = l >> 3;
  const int sub = (l & 7) ^ rof;
  const int arow = wm * 64 + (l & 15);
  const int brow = wn * 64 + (l & 15);

  f32x4 acc[4][4];
#pragma unroll
  for (int i = 0; i < 4; i++)
#pragma unroll
    for (int j = 0; j < 4; j++) acc[i][j] = (f32x4){0.f, 0.f, 0.f, 0.f};

  stageT<V, PL>(Asrc, Bsrc, lds, img, m0, n0, 0, w, rof, sub);
  int c = 0;
  for (int kt = 0; kt < KT; ++kt) {
    if (kt + 1 < KT) {
      stageT<V, PL>(Asrc, Bsrc, lds + (c ^ 1) * BUF, img, m0, n0, kt + 1, w, rof, sub);
      asm volatile("s_waitcnt vmcnt(%0)" :: "n"(PL * 8) : "memory");
    } else {
      asm volatile("s_waitcnt vmcnt(0)" ::: "memory");
    }
    __builtin_amdgcn_s_barrier();
    const u16* Al = lds + c * BUF;
    const u16* Bl = Al + PL * 8192;
#pragma unroll
    for (int kk = 0; kk < 2; ++kk) {
      const int slot = ((kk * 4 + (l >> 4)) ^ (l & 7)) * 8;
      f16x8 af[4][PL], bf[4][PL];
#pragma unroll
      for (int fm = 0; fm < 4; ++fm)
#pragma unroll
        for (int p = 0; p < PL; ++p)
          af[fm][p] = *(const f16x8*)&Al[p * 8192 + (arow + fm * 16) * 64 + slot];
#pragma unroll
      for (int fn = 0; fn < 4; ++fn)
#pragma unroll
        for (int p = 0; p < PL; ++p)
          bf[fn][p] = *(const f16x8*)&Bl[p * 8192 + (brow + fn * 16) * 64 + slot];
#pragma unroll
      for (int fm = 0; fm < 4; ++fm)
#pragma unroll
        for (int fn = 0; fn < 4; ++fn) {
          f32x4 a = acc[fm][fn];
          if constexpr (PL == 2) {
            a = __builtin_amdgcn_mfma_f32_16x16x32_f16(af[fm][1], bf[fn][0], a, 0, 0, 0);
            a = __builtin_amdgcn_mfma_f32_16x16x32_f16(af[fm][0], bf[fn][1], a, 0, 0, 0);
            a = __builtin_amdgcn_mfma_f32_16x16x32_f16(af[fm][0], bf[fn][0], a, 0, 0, 0);
          } else {
            a = __builtin_amdgcn_mfma_f32_16x16x32_f16(af[fm][0], bf[fn][0], a, 0, 0, 0);
          }
          acc[fm][fn] = a;
        }
    }
    asm volatile("" ::: "memory");
    __builtin_amdgcn_s_barrier();
    c ^= 1;
  }

  // ---- epilogue ----
  const int rowL = (l >> 4) * 4;
  const int colL = l & 15;
#pragma unroll
  for (int fm = 0; fm < 4; ++fm)
#pragma unroll
    for (int fn = 0; fn < 4; ++fn) {
      int gcol = n0 + wn * 64 + fn * 16 + colL;
      int rbase = m0 + wm * 64 + fm * 16 + rowL;
      if constexpr (V == 1) {
        if (gcol < 320) {
          u32* T1u = (u32*)o0;
#pragma unroll
          for (int i = 0; i < 4; i += 2) {
            int rho = rbase + i;
            int v = rho >> 1;
            u16 h0, l0, h1, l1;
            split2(acc[fm][fn][i], h0, l0);
            split2(acc[fm][fn][i + 1], h1, l1);
            size_t off = (size_t)img * 61440u + (size_t)v * 320 + gcol;
            T1u[off] = (u32)h0 | ((u32)h1 << 16);
            T1u[3932160u + off] = (u32)l0 | ((u32)l1 << 16);
          }
        }
      } else if constexpr (V == 2) {
#pragma unroll
        for (int i = 0; i < 4; ++i) {
          int vg = rbase + i;
          if (vg < 160)
            oF[(size_t)img * 102400u + (size_t)vg * 640 + gcol] = acc[fm][fn][i];
        }
      } else if constexpr (V == 3) {
        if (gcol < 320) {
#pragma unroll
          for (int i = 0; i < 4; ++i) {
            int mg = rbase + i;
            size_t off = (size_t)img * 81920u + (size_t)mg * 320 + gcol;
            o0[off] = f2h(acc[fm][fn][i] * S_P3);
          }
        }
      } else {
        // write D as 2 fp16 planes [img][px] for expand_mfma
#pragma unroll
        for (int i = 0; i < 4; ++i) {
          int mg = rbase + i;
          u16 h, lo;
          split2(acc[fm][fn][i] * S_P4, h, lo);
          size_t off = (size_t)img * 65536u + (size_t)mg * 256 + gcol;
          o0[off] = h;
          o0[4194304u + off] = lo;
        }
      }
    }
}

extern "C" void kernel_launch(void* const* d_in, const int* in_sizes, int n_in,
                              void* d_out, int out_size, void* d_ws, size_t ws_size,
                              hipStream_t stream) {
  (void)in_sizes; (void)n_in; (void)out_size; (void)ws_size;
  const float* x        = (const float*)d_in[0];
  const float* kernel   = (const float*)d_in[1];
  const float* w_reduce = (const float*)d_in[2];
  const float* b_reduce = (const float*)d_in[3];
  const float* w_g1     = (const float*)d_in[4];
  const float* b_g1     = (const float*)d_in[5];
  const float* w_g2     = (const float*)d_in[6];
  const float* b_g2     = (const float*)d_in[7];
  const float* w_g3     = (const float*)d_in[8];
  const float* b_g3     = (const float*)d_in[9];
  const float* w_g4     = (const float*)d_in[10];
  const float* b_g4     = (const float*)d_in[11];
  const float* w_expand = (const float*)d_in[12];
  const float* b_expand = (const float*)d_in[13];
  float* out = (float*)d_out;

  // ---- workspace layout (float offsets); all aliases time-disjoint ----
  float* ws_f = (float*)d_ws;
  float* cls   = ws_f;
  float* gA    = ws_f + 4194304;
  float* gB    = ws_f + 8323328;
  u16*  padsp  = (u16*)(ws_f + 4194304);
  u16*  T1e    = (u16*)(ws_f + 12452352);
  float* Gt    = ws_f;
  u16*  Ge     = (u16*)(ws_f + 12452352);
  u16*  E2     = (u16*)ws_f;
  u16*  Dh     = (u16*)(ws_f + 5242880);      // [2][64][65536] u16 fp16 planes
  float2* tw   = (float2*)(ws_f + 28180992);
  float2* Kf2  = (float2*)(ws_f + 28182016);
  u16*  Wx1    = (u16*)(ws_f + 28540416);
  u16*  We     = (u16*)(ws_f + 28663296);
  u16*  B4t    = (u16*)(ws_f + 29072896);
  float* poolb = ws_f + 29154816;
  float* kpb   = ws_f + 29155392;

  // ---- static tables (single fused launch) ----
  tables_k<<<dim3(1600), 256, 0, stream>>>(tw, Wx1, We, B4t);

  // ---- reduce via MFMA ----
  reduce_mfma_k<<<dim3(1024), 256, 0, stream>>>(x, w_reduce, b_reduce, cls);
  // ---- conv chain ----
  conv3_k<<<dim3((254 * 254 + 255) / 256, NB), 256, 0, stream>>>(cls, w_g1, b_g1, gA, 256, 256, 1);
  conv3_k<<<dim3((252 * 252 + 255) / 256, NB), 256, 0, stream>>>(gA, w_g2, b_g2, gB, 254, 254, 1);
  conv3_k<<<dim3((250 * 250 + 255) / 256, NB), 256, 0, stream>>>(gB, w_g3, b_g3, gA, 252, 252, 0);
  pool_k<<<dim3(NB * 16 * 9), 256, 0, stream>>>(gA, poolb);
  kp_k<<<dim3(NB), 256, 0, stream>>>(poolb, w_g4, b_g4, kpb);

  // ---- pad + split, Kf ----
  padsplit_k<<<dim3(30720), 256, 0, stream>>>(cls, padsp);
  kf_k<<<dim3((298 * 150 + 255) / 256, NB), 256, 0, stream>>>(kernel, tw, Kf2);

  // ---- P1: T1e = Wx1 x pad^T  (2-plane, 3-product; 576 blocks) ----
  gemmF<1><<<dim3(576), 256, 0, stream>>>(Wx1, padsp, nullptr, T1e, 3, 9, 5);
  // ---- P2: Gt = T1e x We^T  (2-plane, 3-product; 640 blocks) ----
  gemmF<2><<<dim3(640), 256, 0, stream>>>(T1e, We, Gt, nullptr, 5, 10, 10);
  // ---- Wiener + expand -> Ge (single plane, scaled 1/64) ----
  gmul_k<<<dim3(240, IMGS), 256, 0, stream>>>(Gt, Kf2, kpb, tw, (u32*)Ge);
  // ---- P3: E = We(rows 2(m+21)) x Ge^T  (1-plane; 384 blocks) ----
  gemmF<3><<<dim3(384), 256, 0, stream>>>(We, Ge, nullptr, E2, 3, 6, 10);
  // ---- P4: D = E2 x B4t^T -> Dh fp16 planes  (1-plane; 256 blocks) ----
  gemmF<4><<<dim3(256), 256, 0, stream>>>(E2, B4t, nullptr, Dh, 2, 4, 5);
  // ---- expand via MFMA ----
  expand_mfma_k<<<dim3(1024), 256, 0, stream>>>(Dh, w_expand, b_expand, out);
}

// Round 12
// 324.998 us; speedup vs baseline: 1.1697x; 1.1653x over previous
//
#include <hip/hip_runtime.h>
#include <math.h>

typedef unsigned short u16;
typedef unsigned int   u32;
typedef _Float16 f16x8 __attribute__((ext_vector_type(8)));
typedef __attribute__((ext_vector_type(4))) float f32x4;

#define NB    4
#define IMGS  64
#define DSLAB (256*256)
#define TWO_PI 6.283185307179586f

// Scale plan (pipeline linear in pad; total compensated exactly in P4):
#define S_WX1  0.015625f
#define S_GMUL 0.015625f
#define S_P3   0.0625f
#define S_P4   (65536.0f / 88804.0f)

// ---------- fp16 2-way split ----------
__device__ __forceinline__ void split2(float x, u16& h, u16& l) {
  _Float16 hh = (_Float16)x;
  float r = x - (float)hh;
  _Float16 ll = (_Float16)r;
  h = *(u16*)&hh; l = *(u16*)&ll;
}
__device__ __forceinline__ u16 f2h(float x) {
  _Float16 hh = (_Float16)x;
  return *(u16*)&hh;
}

// ---------- async global->LDS 16B DMA ----------
__device__ __forceinline__ void gload16(const u16* g, u16* l) {
  __builtin_amdgcn_global_load_lds(
      (__attribute__((address_space(1))) void*)(g),
      (__attribute__((address_space(3))) void*)(l),
      16, 0, 0);
}

// ---------- fused static tables + kernel-DFT row factor R ----------
// R[b][i][v] = sum_j ker[b,i,j] * exp(-2pi*I*v*(j-10)/298), b<4,i<21,v<150
__global__ __launch_bounds__(256) void tables_k(float2* __restrict__ tw,
                                                u16* __restrict__ Wx1,
                                                u16* __restrict__ We,
                                                u16* __restrict__ B4t,
                                                const float* __restrict__ ker,
                                                float2* __restrict__ Rb) {
  int idx = blockIdx.x * 256 + threadIdx.x;
  if (idx < 298) {
    float ang = (-TWO_PI / 298.0f) * (float)idx;
    float s, c; sincosf(ang, &s, &c);
    tw[idx] = make_float2(c, s);
  }
  if (idx < 12600) {   // R factor
    int b = idx / 3150, rem = idx % 3150;
    int i = rem / 150, v = rem % 150;
    int tt = (2980 - 10 * v) % 298;
    float rr = 0.f, ri = 0.f;
#pragma unroll
    for (int j = 0; j < 21; ++j) {
      float ang = (-TWO_PI / 298.0f) * (float)tt;
      float sn, cs; sincosf(ang, &sn, &cs);
      float kv = ker[b * 441 + i * 21 + j];
      rr = fmaf(kv, cs, rr); ri = fmaf(kv, sn, ri);
      tt += v; if (tt >= 298) tt -= 298;
    }
    Rb[idx] = make_float2(rr, ri);
  }
  if (idx < 122880) {   // Wx1 [2][384][320]
    int rho = idx / 320, n = idx % 320;
    float val = 0.f;
    if (rho < 300 && n < 298) {
      int v = rho >> 1, s = rho & 1;
      int m = (v * n) % 298;
      float ph = (TWO_PI / 298.0f) * (float)m;
      float sn, cs; sincosf(ph, &sn, &cs);
      val = (s ? sn : cs) * S_WX1;
    }
    u16 h, l; split2(val, h, l);
    Wx1[idx] = h; Wx1[122880 + idx] = l;
  }
  if (idx < 409600) {   // We [2][640][640]
    int j2 = idx / 640, k = idx % 640;
    int u = j2 >> 1, pc = j2 & 1;
    int mm = k >> 1, p = k & 1;
    float val = 0.f;
    if (u < 298 && mm < 298) {
      int m = (u * mm) % 298;
      float ph = (TWO_PI / 298.0f) * (float)m;
      float sn, cs; sincosf(ph, &sn, &cs);
      val = (pc == 0) ? (p == 0 ? cs : -sn) : (p == 0 ? -sn : -cs);
    }
    u16 h, l; split2(val, h, l);
    We[idx] = h; We[409600 + idx] = l;
  }
  if (idx < 40960) {    // B4t [1][256][320]
    int v = idx / 256, n = idx % 256;
    float re = 0.f, im = 0.f;
    if (v < 150) {
      int m = (v * (n + 21)) % 298;
      float ang = (-TWO_PI / 298.0f) * (float)m;
      float s, c; sincosf(ang, &s, &c);
      float fac = (v >= 1 && v < 149) ? 2.f : 1.f;
      re = fac * c; im = fac * s;
    }
    size_t o = (size_t)n * 320 + 2 * v;
    B4t[o] = f2h(re); B4t[o + 1] = f2h(im);
  }
}

// ---------- 1x1 reduce conv via MFMA ----------
__global__ __launch_bounds__(256) void reduce_mfma_k(const float* __restrict__ x,
                                                     const float* __restrict__ w,
                                                     const float* __restrict__ bias,
                                                     float* __restrict__ cls) {
  __shared__ u16 Wp[2 * 1024];
  __shared__ float bs[16];
  int t = threadIdx.x;
  for (int i = t; i < 1024; i += 256) {
    u16 h, l; split2(w[i], h, l);
    Wp[i] = h; Wp[1024 + i] = l;
  }
  if (t < 16) bs[t] = bias[t];
  __syncthreads();
  const int b = blockIdx.x >> 8;
  const int px0 = (blockIdx.x & 255) * 256;
  const int l = t & 63, wv = t >> 6;
  const int pxb = px0 + wv * 64;
  const int kgrp = l >> 4;
  f16x8 af[2][2];
#pragma unroll
  for (int kt = 0; kt < 2; ++kt)
#pragma unroll
    for (int p = 0; p < 2; ++p)
      af[kt][p] = *(const f16x8*)&Wp[p * 1024 + (l & 15) * 64 + kt * 32 + kgrp * 8];
  const float* xb = x + (size_t)b * 64 * 65536;
  float xv[2][4][8];
#pragma unroll
  for (int kt = 0; kt < 2; ++kt)
#pragma unroll
    for (int pxf = 0; pxf < 4; ++pxf) {
      int px = pxb + pxf * 16 + (l & 15);
      const float* p0 = xb + (size_t)(kt * 32 + kgrp * 8) * 65536 + px;
#pragma unroll
      for (int j = 0; j < 8; ++j) xv[kt][pxf][j] = p0[(size_t)j * 65536];
    }
  f32x4 acc[4];
#pragma unroll
  for (int i = 0; i < 4; ++i) acc[i] = (f32x4){0.f, 0.f, 0.f, 0.f};
#pragma unroll
  for (int kt = 0; kt < 2; ++kt)
#pragma unroll
    for (int pxf = 0; pxf < 4; ++pxf) {
      f16x8 bh, bl;
#pragma unroll
      for (int j = 0; j < 8; ++j) {
        float v = xv[kt][pxf][j];
        _Float16 hh = (_Float16)v;
        _Float16 ll = (_Float16)(v - (float)hh);
        bh[j] = hh; bl[j] = ll;
      }
      f32x4 a = acc[pxf];
      a = __builtin_amdgcn_mfma_f32_16x16x32_f16(af[kt][0], bl, a, 0, 0, 0);
      a = __builtin_amdgcn_mfma_f32_16x16x32_f16(af[kt][1], bh, a, 0, 0, 0);
      a = __builtin_amdgcn_mfma_f32_16x16x32_f16(af[kt][0], bh, a, 0, 0, 0);
      acc[pxf] = a;
    }
  float* ob = cls + (size_t)b * 16 * 65536;
#pragma unroll
  for (int pxf = 0; pxf < 4; ++pxf) {
    int px = pxb + pxf * 16 + (l & 15);
#pragma unroll
    for (int i = 0; i < 4; ++i) {
      int oc = kgrp * 4 + i;
      ob[(size_t)oc * 65536 + px] = acc[pxf][i] + bs[oc];
    }
  }
}

// ---------- 1x1 expand conv via MFMA ----------
__global__ __launch_bounds__(256) void expand_mfma_k(const u16* __restrict__ Dh,
                                                     const float* __restrict__ w,
                                                     const float* __restrict__ bias,
                                                     float* __restrict__ out) {
  __shared__ u16 Wp[2 * 2048];
  __shared__ float bs[64];
  int t = threadIdx.x;
  for (int i = t; i < 2048; i += 256) {
    int oc = i >> 5, k = i & 31;
    float v = (k < 16) ? w[oc * 16 + k] : 0.f;
    u16 h, l; split2(v, h, l);
    Wp[i] = h; Wp[2048 + i] = l;
  }
  if (t < 64) bs[t] = bias[t];
  __syncthreads();
  const int b = blockIdx.x >> 8;
  const int px0 = (blockIdx.x & 255) * 256;
  const int l = t & 63, wv = t >> 6;
  const int pxb = px0 + wv * 64;
  const int kgrp = l >> 4;
  f16x8 af[4][2];
#pragma unroll
  for (int mf = 0; mf < 4; ++mf)
#pragma unroll
    for (int p = 0; p < 2; ++p)
      af[mf][p] = *(const f16x8*)&Wp[p * 2048 + (mf * 16 + (l & 15)) * 32 + kgrp * 8];
  const int chb = kgrp * 8;
  f32x4 acc[4][4];
#pragma unroll
  for (int i = 0; i < 4; ++i)
#pragma unroll
    for (int j = 0; j < 4; ++j) acc[i][j] = (f32x4){0.f, 0.f, 0.f, 0.f};
#pragma unroll
  for (int pxf = 0; pxf < 4; ++pxf) {
    int px = pxb + pxf * 16 + (l & 15);
    f16x8 bh, bl;
#pragma unroll
    for (int j = 0; j < 8; ++j) {
      _Float16 hv = (_Float16)0.f, lv = (_Float16)0.f;
      if (chb < 16) {
        size_t off = (size_t)(b * 16 + chb + j) * 65536 + px;
        hv = *(const _Float16*)&Dh[off];
        lv = *(const _Float16*)&Dh[4194304u + off];
      }
      bh[j] = hv; bl[j] = lv;
    }
#pragma unroll
    for (int mf = 0; mf < 4; ++mf) {
      f32x4 a = acc[pxf][mf];
      a = __builtin_amdgcn_mfma_f32_16x16x32_f16(af[mf][0], bl, a, 0, 0, 0);
      a = __builtin_amdgcn_mfma_f32_16x16x32_f16(af[mf][1], bh, a, 0, 0, 0);
      a = __builtin_amdgcn_mfma_f32_16x16x32_f16(af[mf][0], bh, a, 0, 0, 0);
      acc[pxf][mf] = a;
    }
  }
  float* ob = out + (size_t)b * 64 * 65536;
#pragma unroll
  for (int pxf = 0; pxf < 4; ++pxf) {
    int px = pxb + pxf * 16 + (l & 15);
#pragma unroll
    for (int mf = 0; mf < 4; ++mf)
#pragma unroll
      for (int i = 0; i < 4; ++i) {
        int oc = mf * 16 + kgrp * 4 + i;
        ob[(size_t)oc * 65536 + px] = acc[pxf][mf][i] + bs[oc];
      }
  }
}

// ---------- 3x3 VALID conv ----------
__global__ __launch_bounds__(256) void conv3_k(const float* __restrict__ in,
                                               const float* __restrict__ w,
                                               const float* __restrict__ bias,
                                               float* __restrict__ out,
                                               int HI, int WI, int relu) {
  __shared__ float ws_[2304];
  __shared__ float bs_[16];
  int t = threadIdx.x;
  for (int i = t; i < 2304; i += 256) ws_[i] = w[i];
  if (t < 16) bs_[t] = bias[t];
  __syncthreads();
  int HO = HI - 2, WO = WI - 2;
  int b = blockIdx.y;
  int idx = blockIdx.x * 256 + t;
  if (idx >= HO * WO) return;
  int y = idx / WO, xx = idx % WO;
  const float* ib = in + ((size_t)b * 16) * (size_t)(HI * WI);
  float acc[16];
#pragma unroll
  for (int c = 0; c < 16; c++) acc[c] = bs_[c];
  for (int ci = 0; ci < 16; ci++) {
    const float* p = ib + (size_t)ci * (HI * WI) + (size_t)y * WI + xx;
#pragma unroll
    for (int dy = 0; dy < 3; dy++) {
#pragma unroll
      for (int dx = 0; dx < 3; dx++) {
        float v = p[dy * WI + dx];
        int widx = ci * 9 + dy * 3 + dx;
#pragma unroll
        for (int co = 0; co < 16; co++)
          acc[co] = fmaf(ws_[co * 144 + widx], v, acc[co]);
      }
    }
  }
  float* ob = out + ((size_t)b * 16) * (size_t)(HO * WO) + (size_t)y * WO + xx;
#pragma unroll
  for (int co = 0; co < 16; co++) {
    float v = acc[co];
    if (relu) v = v > 0.f ? v : 0.1f * v;
    ob[(size_t)co * (HO * WO)] = v;
  }
}

// ---------- adaptive avg pool 250x250 -> 3x3 ----------
__global__ __launch_bounds__(256) void pool_k(const float* __restrict__ g,
                                              float* __restrict__ poolo) {
  int blk = blockIdx.x;
  int bc = blk / 9;
  int ij = blk % 9;
  int i = ij / 3, j = ij % 3;
  const int r0s[3] = {0, 83, 166}, r1s[3] = {84, 167, 250};
  int r0 = r0s[i], r1 = r1s[i], c0 = r0s[j], c1 = r1s[j];
  const float* p = g + (size_t)bc * 62500;
  int nc = c1 - c0;
  int tot = (r1 - r0) * nc;
  float s = 0.f;
  for (int e = threadIdx.x; e < tot; e += 256) {
    int rr = e / nc, cc = e % nc;
    s += p[(r0 + rr) * 250 + c0 + cc];
  }
  for (int off = 32; off > 0; off >>= 1) s += __shfl_down(s, off, 64);
  __shared__ float red[4];
  int lane = threadIdx.x & 63, wid = threadIdx.x >> 6;
  if (lane == 0) red[wid] = s;
  __syncthreads();
  if (threadIdx.x == 0) poolo[blk] = (red[0] + red[1] + red[2] + red[3]) / (float)tot;
}

// ---------- kernel_P ----------
__global__ __launch_bounds__(256) void kp_k(const float* __restrict__ poolv,
                                            const float* __restrict__ w4,
                                            const float* __restrict__ b4,
                                            float* __restrict__ kp) {
  int b = blockIdx.x;
  int t = threadIdx.x;
  __shared__ float vals[144];
  __shared__ float w_[256];
  __shared__ float bb[16];
  if (t < 256) w_[t] = w4[t];
  if (t < 16) bb[t] = b4[t];
  __syncthreads();
  if (t < 144) {
    int c = t / 9, ij = t % 9;
    float a = bb[c];
    for (int k = 0; k < 16; k++)
      a = fmaf(w_[c * 16 + k], poolv[b * 144 + k * 9 + ij], a);
    vals[t] = expf(a);
  }
  __syncthreads();
  if (t < 144) {
    int c = t / 9;
    float m = 0.f;
#pragma unroll
    for (int q = 0; q < 9; q++) m += vals[c * 9 + q];
    kp[b * 144 + t] = vals[t] - m * (1.0f / 9.0f);
  }
}

// ---------- pad (edge) + split2 into [2][64][384][320] fp16 ----------
__global__ __launch_bounds__(256) void padsplit_k(const float* __restrict__ cls,
                                                  u16* __restrict__ p0) {
  size_t idx = (size_t)blockIdx.x * 256 + threadIdx.x;
  if (idx >= 7864320u) return;
  int n = (int)(idx % 320);
  size_t rest = idx / 320;
  int m = (int)(rest % 384);
  size_t img = rest / 384;
  float val = 0.f;
  if (m < 298 && n < 298) {
    int sy = min(max(m - 21, 0), 255);
    int sx = min(max(n - 21, 0), 255);
    val = cls[img * 65536 + (size_t)sy * 256 + sx];
  }
  u16 h, l; split2(val, h, l);
  p0[idx] = h;
  p0[7864320u + idx] = l;
}

// ---------- Kf via separable factor: Kf[u,v] = sum_i tw[u(i-10)] * R[i][v] ---
__global__ __launch_bounds__(256) void kf_k(const float2* __restrict__ Rb,
                                            const float2* __restrict__ tw,
                                            float2* __restrict__ Kf) {
  int b = blockIdx.y;
  int uv = blockIdx.x * 256 + threadIdx.x;
  if (uv >= 298 * 150) return;
  int u = uv / 150, v = uv % 150;
  int tt = (2980 - 10 * u) % 298;
  const float2* Rp = Rb + b * 3150 + v;
  float ar = 0.f, ai = 0.f;
#pragma unroll
  for (int i = 0; i < 21; ++i) {
    float2 wv = tw[tt];
    float2 r = Rp[i * 150];
    ar += wv.x * r.x - wv.y * r.y;
    ai += wv.x * r.y + wv.y * r.x;
    tt += u; if (tt >= 298) tt -= 298;
  }
  Kf[(size_t)b * 44700 + uv] = make_float2(ar, ai);
}

// ---------- Wiener on Gt[v][u] fp32 -> Ge [1][64][384][640] fp16 expanded ----
__global__ __launch_bounds__(256) void gmul_k(const float* __restrict__ Gt,
                                              const float2* __restrict__ Kf,
                                              const float* __restrict__ kp,
                                              const float2* __restrict__ tw,
                                              u32* __restrict__ Geu) {
  int img = blockIdx.y;
  int b = img >> 4;
  __shared__ float kps[9];
  if (threadIdx.x < 9) kps[threadIdx.x] = kp[img * 9 + threadIdx.x];
  __syncthreads();
  int idx = blockIdx.x * 256 + threadIdx.x;
  if (idx >= 192 * 320) return;
  int u = idx % 320, v = idx / 320;
  float gr = 0.f, gi = 0.f;
  if (v < 150 && u < 298) {
    const float* gp = Gt + (size_t)img * 102400 + (size_t)v * 640 + 2 * u;
    float fr = gp[0], fi = gp[1];
    int um = (u == 0) ? 0 : (298 - u);
    int vm = (v == 0) ? 0 : (298 - v);
    int iu[3] = {um, 0, u}, jv[3] = {vm, 0, v};
    float pr = 0.f, pi = 0.f;
#pragma unroll
    for (int i = 0; i < 3; i++) {
#pragma unroll
      for (int j = 0; j < 3; j++) {
        int tt = iu[i] + jv[j];
        if (tt >= 298) tt -= 298;
        float kv = kps[i * 3 + j];
        float2 wv = tw[tt];
        pr = fmaf(kv, wv.x, pr);
        pi = fmaf(kv, wv.y, pi);
      }
    }
    float2 kf = Kf[(size_t)b * 44700 + (size_t)u * 150 + v];
    float denom = kf.x * kf.x + kf.y * kf.y + pr * pr + pi * pi;
    float inv = 1.0f / denom;
    float ir = kf.x * inv, ii = -kf.y * inv;
    gr = (ir * fr - ii * fi) * S_GMUL;
    gi = (ir * fi + ii * fr) * S_GMUL;
  }
  u16 ghr = f2h(gr), ghi = f2h(gi);
  size_t base = (size_t)img * 122880 + (size_t)(2 * v) * 320 + u;
  Geu[base]       = (u32)ghr | ((u32)ghi << 16);
  Geu[base + 320] = (u32)ghi | ((u32)(ghr ^ 0x8000u) << 16);
}

// ---------- staging helper (one K-tile, one buffer) ----------
template <int V, int PL, int MR, int NR>
__device__ __forceinline__ void stageT(const u16* __restrict__ Asrc,
                                       const u16* __restrict__ Bsrc,
                                       u16* Lb, int img, int m0, int n0,
                                       int kt, int w, int rof, int sub) {
  const int kb = kt * 64;
  u16* Al = Lb;
  u16* Bl = Lb + PL * 32 * MR * 64;
#pragma unroll
  for (int i = 0; i < PL * MR; ++i) {
    int q = w + i * 4;
    int p = q / (4 * MR);
    int j = q % (4 * MR);
    int r = j * 8 + rof;
    const u16* ga;
    if constexpr (V == 1) {
      ga = Asrc + (size_t)p * 122880u + (size_t)(m0 + r) * 320 + kb + sub * 8;
    } else if constexpr (V == 2) {
      ga = Asrc + (size_t)p * 7864320u + (size_t)img * 122880u +
           (size_t)(m0 + r) * 640 + kb + sub * 8;
    } else if constexpr (V == 3) {
      ga = Asrc + (size_t)(2 * (m0 + r + 21)) * 640 + kb + sub * 8;
    } else {
      ga = Asrc + (size_t)img * 81920u + (size_t)(m0 + r) * 320 + kb + sub * 8;
    }
    gload16(ga, Al + q * 512);
  }
#pragma unroll
  for (int i = 0; i < PL * NR; ++i) {
    int q = w + i * 4;
    int p = q / (4 * NR);
    int j = q % (4 * NR);
    int rr = j * 8 + rof;
    const u16* gb;
    if constexpr (V == 1) {
      gb = Bsrc + (size_t)p * 7864320u + (size_t)img * 122880u +
           (size_t)(n0 + rr) * 320 + kb + sub * 8;
    } else if constexpr (V == 2) {
      gb = Bsrc + (size_t)p * 409600u + (size_t)(n0 + rr) * 640 + kb + sub * 8;
    } else if constexpr (V == 3) {
      gb = Bsrc + (size_t)img * 245760u + (size_t)(n0 + rr) * 640 + kb + sub * 8;
    } else {
      gb = Bsrc + (size_t)(n0 + rr) * 320 + kb + sub * 8;
    }
    gload16(gb, Bl + q * 512);
  }
}

// ---------- fp16-split MFMA GEMM: dbuf + counted vmcnt + XCD swizzle --------
// Block tile (32*MR) x (32*NR), BK=64, 4 waves (2x2), wave tile (16MR)x(16NR).
template <int V, int MR, int NR>
__global__ __launch_bounds__(256) void gemmF(
    const u16* __restrict__ Asrc, const u16* __restrict__ Bsrc,
    float* __restrict__ oF, u16* __restrict__ o0,
    int nbn, int npi, int KT) {
  constexpr int PL = (V <= 2) ? 2 : 1;
  constexpr int ASZ = PL * 32 * MR * 64;
  constexpr int BSZ = PL * 32 * NR * 64;
  constexpr int BUF = ASZ + BSZ;
  __shared__ u16 lds[2 * BUF];
  const int tid = threadIdx.x;
  const int nwg = gridDim.x;
  const int wg = blockIdx.x;
  const int vid = (wg & 7) * (nwg >> 3) + (wg >> 3);
  const int img = vid / npi;
  const int rem = vid % npi;
  const int m0 = (rem / nbn) * (32 * MR);
  const int n0 = (rem % nbn) * (32 * NR);
  const int l = tid & 63;
  const int w = tid >> 6;
  const int wm = w & 1, wn = w >> 1;
  const int rof = l >> 3;
  const int sub = (l & 7) ^ rof;
  const int arow = wm * (16 * MR) + (l & 15);
  const int brow = wn * (16 * NR) + (l & 15);

  f32x4 acc[MR][NR];
#pragma unroll
  for (int i = 0; i < MR; i++)
#pragma unroll
    for (int j = 0; j < NR; j++) acc[i][j] = (f32x4){0.f, 0.f, 0.f, 0.f};

  stageT<V, PL, MR, NR>(Asrc, Bsrc, lds, img, m0, n0, 0, w, rof, sub);
  int c = 0;
  for (int kt = 0; kt < KT; ++kt) {
    if (kt + 1 < KT) {
      stageT<V, PL, MR, NR>(Asrc, Bsrc, lds + (c ^ 1) * BUF, img, m0, n0, kt + 1, w, rof, sub);
      asm volatile("s_waitcnt vmcnt(%0)" :: "n"(PL * (MR + NR)) : "memory");
    } else {
      asm volatile("s_waitcnt vmcnt(0)" ::: "memory");
    }
    __builtin_amdgcn_s_barrier();
    const u16* Al = lds + c * BUF;
    const u16* Bl = Al + ASZ;
#pragma unroll
    for (int kk = 0; kk < 2; ++kk) {
      const int slot = ((kk * 4 + (l >> 4)) ^ (l & 7)) * 8;
      f16x8 af[MR][PL], bf[NR][PL];
#pragma unroll
      for (int fm = 0; fm < MR; ++fm)
#pragma unroll
        for (int p = 0; p < PL; ++p)
          af[fm][p] = *(const f16x8*)&Al[p * (32 * MR * 64) + (arow + fm * 16) * 64 + slot];
#pragma unroll
      for (int fn = 0; fn < NR; ++fn)
#pragma unroll
        for (int p = 0; p < PL; ++p)
          bf[fn][p] = *(const f16x8*)&Bl[p * (32 * NR * 64) + (brow + fn * 16) * 64 + slot];
#pragma unroll
      for (int fm = 0; fm < MR; ++fm)
#pragma unroll
        for (int fn = 0; fn < NR; ++fn) {
          f32x4 a = acc[fm][fn];
          if constexpr (PL == 2) {
            a = __builtin_amdgcn_mfma_f32_16x16x32_f16(af[fm][1], bf[fn][0], a, 0, 0, 0);
            a = __builtin_amdgcn_mfma_f32_16x16x32_f16(af[fm][0], bf[fn][1], a, 0, 0, 0);
            a = __builtin_amdgcn_mfma_f32_16x16x32_f16(af[fm][0], bf[fn][0], a, 0, 0, 0);
          } else {
            a = __builtin_amdgcn_mfma_f32_16x16x32_f16(af[fm][0], bf[fn][0], a, 0, 0, 0);
          }
          acc[fm][fn] = a;
        }
    }
    asm volatile("" ::: "memory");
    __builtin_amdgcn_s_barrier();
    c ^= 1;
  }

  // ---- epilogue ----
  const int rowL = (l >> 4) * 4;
  const int colL = l & 15;
#pragma unroll
  for (int fm = 0; fm < MR; ++fm)
#pragma unroll
    for (int fn = 0; fn < NR; ++fn) {
      int gcol = n0 + wn * (16 * NR) + fn * 16 + colL;
      int rbase = m0 + wm * (16 * MR) + fm * 16 + rowL;
      if constexpr (V == 1) {
        if (gcol < 320) {
          u32* T1u = (u32*)o0;
#pragma unroll
          for (int i = 0; i < 4; i += 2) {
            int rho = rbase + i;
            int v = rho >> 1;
            u16 h0, l0, h1, l1;
            split2(acc[fm][fn][i], h0, l0);
            split2(acc[fm][fn][i + 1], h1, l1);
            size_t off = (size_t)img * 61440u + (size_t)v * 320 + gcol;
            T1u[off] = (u32)h0 | ((u32)h1 << 16);
            T1u[3932160u + off] = (u32)l0 | ((u32)l1 << 16);
          }
        }
      } else if constexpr (V == 2) {
#pragma unroll
        for (int i = 0; i < 4; ++i) {
          int vg = rbase + i;
          if (vg < 160)
            oF[(size_t)img * 102400u + (size_t)vg * 640 + gcol] = acc[fm][fn][i];
        }
      } else if constexpr (V == 3) {
        if (gcol < 320) {
#pragma unroll
          for (int i = 0; i < 4; ++i) {
            int mg = rbase + i;
            size_t off = (size_t)img * 81920u + (size_t)mg * 320 + gcol;
            o0[off] = f2h(acc[fm][fn][i] * S_P3);
          }
        }
      } else {
#pragma unroll
        for (int i = 0; i < 4; ++i) {
          int mg = rbase + i;
          u16 h, lo;
          split2(acc[fm][fn][i] * S_P4, h, lo);
          size_t off = (size_t)img * 65536u + (size_t)mg * 256 + gcol;
          o0[off] = h;
          o0[4194304u + off] = lo;
        }
      }
    }
}

extern "C" void kernel_launch(void* const* d_in, const int* in_sizes, int n_in,
                              void* d_out, int out_size, void* d_ws, size_t ws_size,
                              hipStream_t stream) {
  (void)in_sizes; (void)n_in; (void)out_size; (void)ws_size;
  const float* x        = (const float*)d_in[0];
  const float* kernel   = (const float*)d_in[1];
  const float* w_reduce = (const float*)d_in[2];
  const float* b_reduce = (const float*)d_in[3];
  const float* w_g1     = (const float*)d_in[4];
  const float* b_g1     = (const float*)d_in[5];
  const float* w_g2     = (const float*)d_in[6];
  const float* b_g2     = (const float*)d_in[7];
  const float* w_g3     = (const float*)d_in[8];
  const float* b_g3     = (const float*)d_in[9];
  const float* w_g4     = (const float*)d_in[10];
  const float* b_g4     = (const float*)d_in[11];
  const float* w_expand = (const float*)d_in[12];
  const float* b_expand = (const float*)d_in[13];
  float* out = (float*)d_out;

  // ---- workspace layout (float offsets); all aliases time-disjoint ----
  float* ws_f = (float*)d_ws;
  float* cls   = ws_f;
  float* gA    = ws_f + 4194304;
  float* gB    = ws_f + 8323328;
  u16*  padsp  = (u16*)(ws_f + 4194304);
  u16*  T1e    = (u16*)(ws_f + 12452352);
  float* Gt    = ws_f;
  u16*  Ge     = (u16*)(ws_f + 12452352);
  u16*  E2     = (u16*)ws_f;
  u16*  Dh     = (u16*)(ws_f + 5242880);
  float2* tw   = (float2*)(ws_f + 28180992);
  float2* Kf2  = (float2*)(ws_f + 28182016);
  u16*  Wx1    = (u16*)(ws_f + 28540416);
  u16*  We     = (u16*)(ws_f + 28663296);
  u16*  B4t    = (u16*)(ws_f + 29072896);
  float* poolb = ws_f + 29154816;
  float* kpb   = ws_f + 29155392;
  float2* Rb   = (float2*)(ws_f + 29155968);   // 12600 float2

  // ---- static tables + R (single fused launch) ----
  tables_k<<<dim3(1600), 256, 0, stream>>>(tw, Wx1, We, B4t, kernel, Rb);

  // ---- reduce via MFMA ----
  reduce_mfma_k<<<dim3(1024), 256, 0, stream>>>(x, w_reduce, b_reduce, cls);
  // ---- conv chain ----
  conv3_k<<<dim3((254 * 254 + 255) / 256, NB), 256, 0, stream>>>(cls, w_g1, b_g1, gA, 256, 256, 1);
  conv3_k<<<dim3((252 * 252 + 255) / 256, NB), 256, 0, stream>>>(gA, w_g2, b_g2, gB, 254, 254, 1);
  conv3_k<<<dim3((250 * 250 + 255) / 256, NB), 256, 0, stream>>>(gB, w_g3, b_g3, gA, 252, 252, 0);
  pool_k<<<dim3(NB * 16 * 9), 256, 0, stream>>>(gA, poolb);
  kp_k<<<dim3(NB), 256, 0, stream>>>(poolb, w_g4, b_g4, kpb);

  // ---- pad + split, Kf (separable) ----
  padsplit_k<<<dim3(30720), 256, 0, stream>>>(cls, padsp);
  kf_k<<<dim3((298 * 150 + 255) / 256, NB), 256, 0, stream>>>(Rb, tw, Kf2);

  // ---- P1: T1e = Wx1 x pad^T  (M=320, MR=5; 384 blocks) ----
  gemmF<1, 5, 4><<<dim3(384), 256, 0, stream>>>(Wx1, padsp, nullptr, T1e, 3, 6, 5);
  // ---- P2: Gt = T1e x We^T  (M=160 exact, MR=5; 320 blocks) ----
  gemmF<2, 5, 4><<<dim3(320), 256, 0, stream>>>(T1e, We, Gt, nullptr, 5, 5, 10);
  // ---- Wiener + expand -> Ge ----
  gmul_k<<<dim3(240, IMGS), 256, 0, stream>>>(Gt, Kf2, kpb, tw, (u32*)Ge);
  // ---- P3: E = We(rows 2(m+21)) x Ge^T  (N=320 exact, NR=5; 256 blocks) ----
  gemmF<3, 4, 5><<<dim3(256), 256, 0, stream>>>(We, Ge, nullptr, E2, 2, 4, 10);
  // ---- P4: D = E2 x B4t^T -> Dh fp16 planes  (256 blocks) ----
  gemmF<4, 4, 4><<<dim3(256), 256, 0, stream>>>(E2, B4t, nullptr, Dh, 2, 4, 5);
  // ---- expand via MFMA ----
  expand_mfma_k<<<dim3(1024), 256, 0, stream>>>(Dh, w_expand, b_expand, out);
}

// Round 13
// 289.844 us; speedup vs baseline: 1.3116x; 1.1213x over previous
//
#include <hip/hip_runtime.h>
#include <math.h>

typedef unsigned short u16;
typedef unsigned int   u32;
typedef _Float16 f16x8 __attribute__((ext_vector_type(8)));
typedef __attribute__((ext_vector_type(4))) float f32x4;

#define NB    4
#define IMGS  64
#define DSLAB (256*256)
#define TWO_PI 6.283185307179586f

// Scale plan (pipeline linear in pad; total compensated exactly in P4):
#define S_WX1  0.015625f
#define S_GMUL 0.015625f
#define S_P3   0.0625f
#define S_P4   (65536.0f / 88804.0f)

// ---------- fp16 2-way split ----------
__device__ __forceinline__ void split2(float x, u16& h, u16& l) {
  _Float16 hh = (_Float16)x;
  float r = x - (float)hh;
  _Float16 ll = (_Float16)r;
  h = *(u16*)&hh; l = *(u16*)&ll;
}
__device__ __forceinline__ u16 f2h(float x) {
  _Float16 hh = (_Float16)x;
  return *(u16*)&hh;
}

// ---------- async global->LDS 16B DMA ----------
__device__ __forceinline__ void gload16(const u16* g, u16* l) {
  __builtin_amdgcn_global_load_lds(
      (__attribute__((address_space(1))) void*)(g),
      (__attribute__((address_space(3))) void*)(l),
      16, 0, 0);
}

// ---------- fused static tables + kernel-DFT row factor R ----------
__global__ __launch_bounds__(256) void tables_k(float2* __restrict__ tw,
                                                u16* __restrict__ Wx1,
                                                u16* __restrict__ We,
                                                u16* __restrict__ B4t,
                                                const float* __restrict__ ker,
                                                float2* __restrict__ Rb) {
  int idx = blockIdx.x * 256 + threadIdx.x;
  if (idx < 298) {
    float ang = (-TWO_PI / 298.0f) * (float)idx;
    float s, c; sincosf(ang, &s, &c);
    tw[idx] = make_float2(c, s);
  }
  if (idx < 12600) {   // R[b][i][v]
    int b = idx / 3150, rem = idx % 3150;
    int i = rem / 150, v = rem % 150;
    int tt = (2980 - 10 * v) % 298;
    float rr = 0.f, ri = 0.f;
#pragma unroll
    for (int j = 0; j < 21; ++j) {
      float ang = (-TWO_PI / 298.0f) * (float)tt;
      float sn, cs; sincosf(ang, &sn, &cs);
      float kv = ker[b * 441 + i * 21 + j];
      rr = fmaf(kv, cs, rr); ri = fmaf(kv, sn, ri);
      tt += v; if (tt >= 298) tt -= 298;
    }
    Rb[idx] = make_float2(rr, ri);
  }
  if (idx < 122880) {   // Wx1 [2][384][320]
    int rho = idx / 320, n = idx % 320;
    float val = 0.f;
    if (rho < 300 && n < 298) {
      int v = rho >> 1, s = rho & 1;
      int m = (v * n) % 298;
      float ph = (TWO_PI / 298.0f) * (float)m;
      float sn, cs; sincosf(ph, &sn, &cs);
      val = (s ? sn : cs) * S_WX1;
    }
    u16 h, l; split2(val, h, l);
    Wx1[idx] = h; Wx1[122880 + idx] = l;
  }
  if (idx < 409600) {   // We [2][640][640]
    int j2 = idx / 640, k = idx % 640;
    int u = j2 >> 1, pc = j2 & 1;
    int mm = k >> 1, p = k & 1;
    float val = 0.f;
    if (u < 298 && mm < 298) {
      int m = (u * mm) % 298;
      float ph = (TWO_PI / 298.0f) * (float)m;
      float sn, cs; sincosf(ph, &sn, &cs);
      val = (pc == 0) ? (p == 0 ? cs : -sn) : (p == 0 ? -sn : -cs);
    }
    u16 h, l; split2(val, h, l);
    We[idx] = h; We[409600 + idx] = l;
  }
  if (idx < 40960) {    // B4t [1][256][320]
    int v = idx / 256, n = idx % 256;
    float re = 0.f, im = 0.f;
    if (v < 150) {
      int m = (v * (n + 21)) % 298;
      float ang = (-TWO_PI / 298.0f) * (float)m;
      float s, c; sincosf(ang, &s, &c);
      float fac = (v >= 1 && v < 149) ? 2.f : 1.f;
      re = fac * c; im = fac * s;
    }
    size_t o = (size_t)n * 320 + 2 * v;
    B4t[o] = f2h(re); B4t[o + 1] = f2h(im);
  }
}

// ---------- 1x1 reduce conv via MFMA ----------
__global__ __launch_bounds__(256) void reduce_mfma_k(const float* __restrict__ x,
                                                     const float* __restrict__ w,
                                                     const float* __restrict__ bias,
                                                     float* __restrict__ cls) {
  __shared__ u16 Wp[2 * 1024];
  __shared__ float bs[16];
  int t = threadIdx.x;
  for (int i = t; i < 1024; i += 256) {
    u16 h, l; split2(w[i], h, l);
    Wp[i] = h; Wp[1024 + i] = l;
  }
  if (t < 16) bs[t] = bias[t];
  __syncthreads();
  const int b = blockIdx.x >> 8;
  const int px0 = (blockIdx.x & 255) * 256;
  const int l = t & 63, wv = t >> 6;
  const int pxb = px0 + wv * 64;
  const int kgrp = l >> 4;
  f16x8 af[2][2];
#pragma unroll
  for (int kt = 0; kt < 2; ++kt)
#pragma unroll
    for (int p = 0; p < 2; ++p)
      af[kt][p] = *(const f16x8*)&Wp[p * 1024 + (l & 15) * 64 + kt * 32 + kgrp * 8];
  const float* xb = x + (size_t)b * 64 * 65536;
  float xv[2][4][8];
#pragma unroll
  for (int kt = 0; kt < 2; ++kt)
#pragma unroll
    for (int pxf = 0; pxf < 4; ++pxf) {
      int px = pxb + pxf * 16 + (l & 15);
      const float* p0 = xb + (size_t)(kt * 32 + kgrp * 8) * 65536 + px;
#pragma unroll
      for (int j = 0; j < 8; ++j) xv[kt][pxf][j] = p0[(size_t)j * 65536];
    }
  f32x4 acc[4];
#pragma unroll
  for (int i = 0; i < 4; ++i) acc[i] = (f32x4){0.f, 0.f, 0.f, 0.f};
#pragma unroll
  for (int kt = 0; kt < 2; ++kt)
#pragma unroll
    for (int pxf = 0; pxf < 4; ++pxf) {
      f16x8 bh, bl;
#pragma unroll
      for (int j = 0; j < 8; ++j) {
        float v = xv[kt][pxf][j];
        _Float16 hh = (_Float16)v;
        _Float16 ll = (_Float16)(v - (float)hh);
        bh[j] = hh; bl[j] = ll;
      }
      f32x4 a = acc[pxf];
      a = __builtin_amdgcn_mfma_f32_16x16x32_f16(af[kt][0], bl, a, 0, 0, 0);
      a = __builtin_amdgcn_mfma_f32_16x16x32_f16(af[kt][1], bh, a, 0, 0, 0);
      a = __builtin_amdgcn_mfma_f32_16x16x32_f16(af[kt][0], bh, a, 0, 0, 0);
      acc[pxf] = a;
    }
  float* ob = cls + (size_t)b * 16 * 65536;
#pragma unroll
  for (int pxf = 0; pxf < 4; ++pxf) {
    int px = pxb + pxf * 16 + (l & 15);
#pragma unroll
    for (int i = 0; i < 4; ++i) {
      int oc = kgrp * 4 + i;
      ob[(size_t)oc * 65536 + px] = acc[pxf][i] + bs[oc];
    }
  }
}

// ---------- 1x1 expand conv via MFMA ----------
__global__ __launch_bounds__(256) void expand_mfma_k(const u16* __restrict__ Dh,
                                                     const float* __restrict__ w,
                                                     const float* __restrict__ bias,
                                                     float* __restrict__ out) {
  __shared__ u16 Wp[2 * 2048];
  __shared__ float bs[64];
  int t = threadIdx.x;
  for (int i = t; i < 2048; i += 256) {
    int oc = i >> 5, k = i & 31;
    float v = (k < 16) ? w[oc * 16 + k] : 0.f;
    u16 h, l; split2(v, h, l);
    Wp[i] = h; Wp[2048 + i] = l;
  }
  if (t < 64) bs[t] = bias[t];
  __syncthreads();
  const int b = blockIdx.x >> 8;
  const int px0 = (blockIdx.x & 255) * 256;
  const int l = t & 63, wv = t >> 6;
  const int pxb = px0 + wv * 64;
  const int kgrp = l >> 4;
  f16x8 af[4][2];
#pragma unroll
  for (int mf = 0; mf < 4; ++mf)
#pragma unroll
    for (int p = 0; p < 2; ++p)
      af[mf][p] = *(const f16x8*)&Wp[p * 2048 + (mf * 16 + (l & 15)) * 32 + kgrp * 8];
  const int chb = kgrp * 8;
  f32x4 acc[4][4];
#pragma unroll
  for (int i = 0; i < 4; ++i)
#pragma unroll
    for (int j = 0; j < 4; ++j) acc[i][j] = (f32x4){0.f, 0.f, 0.f, 0.f};
#pragma unroll
  for (int pxf = 0; pxf < 4; ++pxf) {
    int px = pxb + pxf * 16 + (l & 15);
    f16x8 bh, bl;
#pragma unroll
    for (int j = 0; j < 8; ++j) {
      _Float16 hv = (_Float16)0.f, lv = (_Float16)0.f;
      if (chb < 16) {
        size_t off = (size_t)(b * 16 + chb + j) * 65536 + px;
        hv = *(const _Float16*)&Dh[off];
        lv = *(const _Float16*)&Dh[4194304u + off];
      }
      bh[j] = hv; bl[j] = lv;
    }
#pragma unroll
    for (int mf = 0; mf < 4; ++mf) {
      f32x4 a = acc[pxf][mf];
      a = __builtin_amdgcn_mfma_f32_16x16x32_f16(af[mf][0], bl, a, 0, 0, 0);
      a = __builtin_amdgcn_mfma_f32_16x16x32_f16(af[mf][1], bh, a, 0, 0, 0);
      a = __builtin_amdgcn_mfma_f32_16x16x32_f16(af[mf][0], bh, a, 0, 0, 0);
      acc[pxf][mf] = a;
    }
  }
  float* ob = out + (size_t)b * 64 * 65536;
#pragma unroll
  for (int pxf = 0; pxf < 4; ++pxf) {
    int px = pxb + pxf * 16 + (l & 15);
#pragma unroll
    for (int mf = 0; mf < 4; ++mf)
#pragma unroll
      for (int i = 0; i < 4; ++i) {
        int oc = mf * 16 + kgrp * 4 + i;
        ob[(size_t)oc * 65536 + px] = acc[pxf][mf][i] + bs[oc];
      }
  }
}

// ---------- 3x3 VALID conv via MFMA (implicit GEMM, fp16 2-split 3-prod) ----
// k = (dy*3+dx)*16 + ci, padded to 160 (5 K-tiles of 32).
// Block = one output row y of one batch; 4 waves x 4 iters x 16 px = 256 px.
__global__ __launch_bounds__(256) void conv3_mfma_k(const float* __restrict__ in,
                                                    const float* __restrict__ w,
                                                    const float* __restrict__ bias,
                                                    float* __restrict__ out,
                                                    int HI, int WI, int relu) {
  __shared__ u16 Wp[2 * 2560];
  __shared__ float bs[16];
  int t = threadIdx.x;
  for (int i = t; i < 2560; i += 256) {
    int oc = i / 160, k = i % 160;
    int dydx = k >> 4, ci = k & 15;
    float v = (dydx < 9) ? w[oc * 144 + ci * 9 + dydx] : 0.f;
    u16 h, l; split2(v, h, l);
    Wp[i] = h; Wp[2560 + i] = l;
  }
  if (t < 16) bs[t] = bias[t];
  __syncthreads();
  const int HO = HI - 2, WO = WI - 2;
  const int y = blockIdx.x;
  const int b = blockIdx.y;
  const int l = t & 63, wv = t >> 6;
  const int pxcol = l & 15, kgrp = l >> 4;
  const int plane = HI * WI;

  // A fragments (weights) in registers: oc = l&15
  f16x8 af[5][2];
#pragma unroll
  for (int kt = 0; kt < 5; ++kt)
#pragma unroll
    for (int p = 0; p < 2; ++p)
      af[kt][p] = *(const f16x8*)&Wp[p * 2560 + (l & 15) * 160 + kt * 32 + kgrp * 8];

  // per-kt (dy,dx) for this lane: dydx = kt*2 + (kgrp>>1)
  int dyA[5], dxA[5], okA[5];
#pragma unroll
  for (int kt = 0; kt < 5; ++kt) {
    int dydx = kt * 2 + (kgrp >> 1);
    okA[kt] = (dydx < 9);
    int dd = okA[kt] ? dydx : 0;
    dyA[kt] = dd / 3; dxA[kt] = dd % 3;
  }
  const int ci0 = (kgrp & 1) * 8;
  const float* ib = in + (size_t)b * 16 * plane + (size_t)ci0 * plane;
  float* ob = out + (size_t)b * 16 * (HO * WO) + (size_t)y * WO;

#pragma unroll
  for (int it = 0; it < 4; ++it) {
    const int x = wv * 64 + it * 16 + pxcol;
    f32x4 acc = (f32x4){0.f, 0.f, 0.f, 0.f};
#pragma unroll
    for (int kt = 0; kt < 5; ++kt) {
      f16x8 bh, bl;
      if (okA[kt]) {
        const float* p0 = ib + (size_t)(y + dyA[kt]) * WI + x + dxA[kt];
#pragma unroll
        for (int j = 0; j < 8; ++j) {
          float v = p0[(size_t)j * plane];
          _Float16 hh = (_Float16)v;
          bh[j] = hh; bl[j] = (_Float16)(v - (float)hh);
        }
      } else {
#pragma unroll
        for (int j = 0; j < 8; ++j) { bh[j] = (_Float16)0.f; bl[j] = (_Float16)0.f; }
      }
      acc = __builtin_amdgcn_mfma_f32_16x16x32_f16(af[kt][0], bl, acc, 0, 0, 0);
      acc = __builtin_amdgcn_mfma_f32_16x16x32_f16(af[kt][1], bh, acc, 0, 0, 0);
      acc = __builtin_amdgcn_mfma_f32_16x16x32_f16(af[kt][0], bh, acc, 0, 0, 0);
    }
    if (x < WO) {
#pragma unroll
      for (int i = 0; i < 4; ++i) {
        int oc = kgrp * 4 + i;
        float v = acc[i] + bs[oc];
        if (relu) v = v > 0.f ? v : 0.1f * v;
        ob[(size_t)oc * (HO * WO) + x] = v;
      }
    }
  }
}

// ---------- adaptive avg pool 250x250 -> 3x3 ----------
__global__ __launch_bounds__(256) void pool_k(const float* __restrict__ g,
                                              float* __restrict__ poolo) {
  int blk = blockIdx.x;
  int bc = blk / 9;
  int ij = blk % 9;
  int i = ij / 3, j = ij % 3;
  const int r0s[3] = {0, 83, 166}, r1s[3] = {84, 167, 250};
  int r0 = r0s[i], r1 = r1s[i], c0 = r0s[j], c1 = r1s[j];
  const float* p = g + (size_t)bc * 62500;
  int nc = c1 - c0;
  int tot = (r1 - r0) * nc;
  float s = 0.f;
  for (int e = threadIdx.x; e < tot; e += 256) {
    int rr = e / nc, cc = e % nc;
    s += p[(r0 + rr) * 250 + c0 + cc];
  }
  for (int off = 32; off > 0; off >>= 1) s += __shfl_down(s, off, 64);
  __shared__ float red[4];
  int lane = threadIdx.x & 63, wid = threadIdx.x >> 6;
  if (lane == 0) red[wid] = s;
  __syncthreads();
  if (threadIdx.x == 0) poolo[blk] = (red[0] + red[1] + red[2] + red[3]) / (float)tot;
}

// ---------- kernel_P ----------
__global__ __launch_bounds__(256) void kp_k(const float* __restrict__ poolv,
                                            const float* __restrict__ w4,
                                            const float* __restrict__ b4,
                                            float* __restrict__ kp) {
  int b = blockIdx.x;
  int t = threadIdx.x;
  __shared__ float vals[144];
  __shared__ float w_[256];
  __shared__ float bb[16];
  if (t < 256) w_[t] = w4[t];
  if (t < 16) bb[t] = b4[t];
  __syncthreads();
  if (t < 144) {
    int c = t / 9, ij = t % 9;
    float a = bb[c];
    for (int k = 0; k < 16; k++)
      a = fmaf(w_[c * 16 + k], poolv[b * 144 + k * 9 + ij], a);
    vals[t] = expf(a);
  }
  __syncthreads();
  if (t < 144) {
    int c = t / 9;
    float m = 0.f;
#pragma unroll
    for (int q = 0; q < 9; q++) m += vals[c * 9 + q];
    kp[b * 144 + t] = vals[t] - m * (1.0f / 9.0f);
  }
}

// ---------- pad (edge) + split2 into [2][64][384][320] fp16 ----------
__global__ __launch_bounds__(256) void padsplit_k(const float* __restrict__ cls,
                                                  u16* __restrict__ p0) {
  size_t idx = (size_t)blockIdx.x * 256 + threadIdx.x;
  if (idx >= 7864320u) return;
  int n = (int)(idx % 320);
  size_t rest = idx / 320;
  int m = (int)(rest % 384);
  size_t img = rest / 384;
  float val = 0.f;
  if (m < 298 && n < 298) {
    int sy = min(max(m - 21, 0), 255);
    int sx = min(max(n - 21, 0), 255);
    val = cls[img * 65536 + (size_t)sy * 256 + sx];
  }
  u16 h, l; split2(val, h, l);
  p0[idx] = h;
  p0[7864320u + idx] = l;
}

// ---------- Kf via separable factor ----------
__global__ __launch_bounds__(256) void kf_k(const float2* __restrict__ Rb,
                                            const float2* __restrict__ tw,
                                            float2* __restrict__ Kf) {
  int b = blockIdx.y;
  int uv = blockIdx.x * 256 + threadIdx.x;
  if (uv >= 298 * 150) return;
  int u = uv / 150, v = uv % 150;
  int tt = (2980 - 10 * u) % 298;
  const float2* Rp = Rb + b * 3150 + v;
  float ar = 0.f, ai = 0.f;
#pragma unroll
  for (int i = 0; i < 21; ++i) {
    float2 wv = tw[tt];
    float2 r = Rp[i * 150];
    ar += wv.x * r.x - wv.y * r.y;
    ai += wv.x * r.y + wv.y * r.x;
    tt += u; if (tt >= 298) tt -= 298;
  }
  Kf[(size_t)b * 44700 + uv] = make_float2(ar, ai);
}

// ---------- Wiener on Gt[v][u] fp32 -> Ge [1][64][384][640] fp16 expanded ----
__global__ __launch_bounds__(256) void gmul_k(const float* __restrict__ Gt,
                                              const float2* __restrict__ Kf,
                                              const float* __restrict__ kp,
                                              const float2* __restrict__ tw,
                                              u32* __restrict__ Geu) {
  int img = blockIdx.y;
  int b = img >> 4;
  __shared__ float kps[9];
  if (threadIdx.x < 9) kps[threadIdx.x] = kp[img * 9 + threadIdx.x];
  __syncthreads();
  int idx = blockIdx.x * 256 + threadIdx.x;
  if (idx >= 192 * 320) return;
  int u = idx % 320, v = idx / 320;
  float gr = 0.f, gi = 0.f;
  if (v < 150 && u < 298) {
    const float* gp = Gt + (size_t)img * 102400 + (size_t)v * 640 + 2 * u;
    float fr = gp[0], fi = gp[1];
    int um = (u == 0) ? 0 : (298 - u);
    int vm = (v == 0) ? 0 : (298 - v);
    int iu[3] = {um, 0, u}, jv[3] = {vm, 0, v};
    float pr = 0.f, pi = 0.f;
#pragma unroll
    for (int i = 0; i < 3; i++) {
#pragma unroll
      for (int j = 0; j < 3; j++) {
        int tt = iu[i] + jv[j];
        if (tt >= 298) tt -= 298;
        float kv = kps[i * 3 + j];
        float2 wv = tw[tt];
        pr = fmaf(kv, wv.x, pr);
        pi = fmaf(kv, wv.y, pi);
      }
    }
    float2 kf = Kf[(size_t)b * 44700 + (size_t)u * 150 + v];
    float denom = kf.x * kf.x + kf.y * kf.y + pr * pr + pi * pi;
    float inv = 1.0f / denom;
    float ir = kf.x * inv, ii = -kf.y * inv;
    gr = (ir * fr - ii * fi) * S_GMUL;
    gi = (ir * fi + ii * fr) * S_GMUL;
  }
  u16 ghr = f2h(gr), ghi = f2h(gi);
  size_t base = (size_t)img * 122880 + (size_t)(2 * v) * 320 + u;
  Geu[base]       = (u32)ghr | ((u32)ghi << 16);
  Geu[base + 320] = (u32)ghi | ((u32)(ghr ^ 0x8000u) << 16);
}

// ---------- staging helper (one K-tile, one buffer) ----------
template <int V, int PL, int MR, int NR>
__device__ __forceinline__ void stageT(const u16* __restrict__ Asrc,
                                       const u16* __restrict__ Bsrc,
                                       u16* Lb, int img, int m0, int n0,
                                       int kt, int w, int rof, int sub) {
  const int kb = kt * 64;
  u16* Al = Lb;
  u16* Bl = Lb + PL * 32 * MR * 64;
#pragma unroll
  for (int i = 0; i < PL * MR; ++i) {
    int q = w + i * 4;
    int p = q / (4 * MR);
    int j = q % (4 * MR);
    int r = j * 8 + rof;
    const u16* ga;
    if constexpr (V == 1) {
      ga = Asrc + (size_t)p * 122880u + (size_t)(m0 + r) * 320 + kb + sub * 8;
    } else if constexpr (V == 2) {
      ga = Asrc + (size_t)p * 7864320u + (size_t)img * 122880u +
           (size_t)(m0 + r) * 640 + kb + sub * 8;
    } else if constexpr (V == 3) {
      ga = Asrc + (size_t)(2 * (m0 + r + 21)) * 640 + kb + sub * 8;
    } else {
      ga = Asrc + (size_t)img * 81920u + (size_t)(m0 + r) * 320 + kb + sub * 8;
    }
    gload16(ga, Al + q * 512);
  }
#pragma unroll
  for (int i = 0; i < PL * NR; ++i) {
    int q = w + i * 4;
    int p = q / (4 * NR);
    int j = q % (4 * NR);
    int rr = j * 8 + rof;
    const u16* gb;
    if constexpr (V == 1) {
      gb = Bsrc + (size_t)p * 7864320u + (size_t)img * 122880u +
           (size_t)(n0 + rr) * 320 + kb + sub * 8;
    } else if constexpr (V == 2) {
      gb = Bsrc + (size_t)p * 409600u + (size_t)(n0 + rr) * 640 + kb + sub * 8;
    } else if constexpr (V == 3) {
      gb = Bsrc + (size_t)img * 245760u + (size_t)(n0 + rr) * 640 + kb + sub * 8;
    } else {
      gb = Bsrc + (size_t)(n0 + rr) * 320 + kb + sub * 8;
    }
    gload16(gb, Bl + q * 512);
  }
}

// ---------- fp16-split MFMA GEMM: dbuf + counted vmcnt + XCD swizzle --------
template <int V, int MR, int NR>
__global__ __launch_bounds__(256) void gemmF(
    const u16* __restrict__ Asrc, const u16* __restrict__ Bsrc,
    float* __restrict__ oF, u16* __restrict__ o0,
    int nbn, int npi, int KT) {
  constexpr int PL = (V <= 2) ? 2 : 1;
  constexpr int ASZ = PL * 32 * MR * 64;
  constexpr int BSZ = PL * 32 * NR * 64;
  constexpr int BUF = ASZ + BSZ;
  __shared__ u16 lds[2 * BUF];
  const int tid = threadIdx.x;
  const int nwg = gridDim.x;
  const int wg = blockIdx.x;
  const int vid = (wg & 7) * (nwg >> 3) + (wg >> 3);
  const int img = vid / npi;
  const int rem = vid % npi;
  const int m0 = (rem / nbn) * (32 * MR);
  const int n0 = (rem % nbn) * (32 * NR);
  const int l = tid & 63;
  const int w = tid >> 6;
  const int wm = w & 1, wn = w >> 1;
  const int rof = l >> 3;
  const int sub = (l & 7) ^ rof;
  const int arow = wm * (16 * MR) + (l & 15);
  const int brow = wn * (16 * NR) + (l & 15);

  f32x4 acc[MR][NR];
#pragma unroll
  for (int i = 0; i < MR; i++)
#pragma unroll
    for (int j = 0; j < NR; j++) acc[i][j] = (f32x4){0.f, 0.f, 0.f, 0.f};

  stageT<V, PL, MR, NR>(Asrc, Bsrc, lds, img, m0, n0, 0, w, rof, sub);
  int c = 0;
  for (int kt = 0; kt < KT; ++kt) {
    if (kt + 1 < KT) {
      stageT<V, PL, MR, NR>(Asrc, Bsrc, lds + (c ^ 1) * BUF, img, m0, n0, kt + 1, w, rof, sub);
      asm volatile("s_waitcnt vmcnt(%0)" :: "n"(PL * (MR + NR)) : "memory");
    } else {
      asm volatile("s_waitcnt vmcnt(0)" ::: "memory");
    }
    __builtin_amdgcn_s_barrier();
    const u16* Al = lds + c * BUF;
    const u16* Bl = Al + ASZ;
#pragma unroll
    for (int kk = 0; kk < 2; ++kk) {
      const int slot = ((kk * 4 + (l >> 4)) ^ (l & 7)) * 8;
      f16x8 af[MR][PL], bf[NR][PL];
#pragma unroll
      for (int fm = 0; fm < MR; ++fm)
#pragma unroll
        for (int p = 0; p < PL; ++p)
          af[fm][p] = *(const f16x8*)&Al[p * (32 * MR * 64) + (arow + fm * 16) * 64 + slot];
#pragma unroll
      for (int fn = 0; fn < NR; ++fn)
#pragma unroll
        for (int p = 0; p < PL; ++p)
          bf[fn][p] = *(const f16x8*)&Bl[p * (32 * NR * 64) + (brow + fn * 16) * 64 + slot];
#pragma unroll
      for (int fm = 0; fm < MR; ++fm)
#pragma unroll
        for (int fn = 0; fn < NR; ++fn) {
          f32x4 a = acc[fm][fn];
          if constexpr (PL == 2) {
            a = __builtin_amdgcn_mfma_f32_16x16x32_f16(af[fm][1], bf[fn][0], a, 0, 0, 0);
            a = __builtin_amdgcn_mfma_f32_16x16x32_f16(af[fm][0], bf[fn][1], a, 0, 0, 0);
            a = __builtin_amdgcn_mfma_f32_16x16x32_f16(af[fm][0], bf[fn][0], a, 0, 0, 0);
          } else {
            a = __builtin_amdgcn_mfma_f32_16x16x32_f16(af[fm][0], bf[fn][0], a, 0, 0, 0);
          }
          acc[fm][fn] = a;
        }
    }
    asm volatile("" ::: "memory");
    __builtin_amdgcn_s_barrier();
    c ^= 1;
  }

  // ---- epilogue ----
  const int rowL = (l >> 4) * 4;
  const int colL = l & 15;
#pragma unroll
  for (int fm = 0; fm < MR; ++fm)
#pragma unroll
    for (int fn = 0; fn < NR; ++fn) {
      int gcol = n0 + wn * (16 * NR) + fn * 16 + colL;
      int rbase = m0 + wm * (16 * MR) + fm * 16 + rowL;
      if constexpr (V == 1) {
        if (gcol < 320) {
          u32* T1u = (u32*)o0;
#pragma unroll
          for (int i = 0; i < 4; i += 2) {
            int rho = rbase + i;
            int v = rho >> 1;
            u16 h0, l0, h1, l1;
            split2(acc[fm][fn][i], h0, l0);
            split2(acc[fm][fn][i + 1], h1, l1);
            size_t off = (size_t)img * 61440u + (size_t)v * 320 + gcol;
            T1u[off] = (u32)h0 | ((u32)h1 << 16);
            T1u[3932160u + off] = (u32)l0 | ((u32)l1 << 16);
          }
        }
      } else if constexpr (V == 2) {
#pragma unroll
        for (int i = 0; i < 4; ++i) {
          int vg = rbase + i;
          if (vg < 160)
            oF[(size_t)img * 102400u + (size_t)vg * 640 + gcol] = acc[fm][fn][i];
        }
      } else if constexpr (V == 3) {
        if (gcol < 320) {
#pragma unroll
          for (int i = 0; i < 4; ++i) {
            int mg = rbase + i;
            size_t off = (size_t)img * 81920u + (size_t)mg * 320 + gcol;
            o0[off] = f2h(acc[fm][fn][i] * S_P3);
          }
        }
      } else {
#pragma unroll
        for (int i = 0; i < 4; ++i) {
          int mg = rbase + i;
          u16 h, lo;
          split2(acc[fm][fn][i] * S_P4, h, lo);
          size_t off = (size_t)img * 65536u + (size_t)mg * 256 + gcol;
          o0[off] = h;
          o0[4194304u + off] = lo;
        }
      }
    }
}

extern "C" void kernel_launch(void* const* d_in, const int* in_sizes, int n_in,
                              void* d_out, int out_size, void* d_ws, size_t ws_size,
                              hipStream_t stream) {
  (void)in_sizes; (void)n_in; (void)out_size; (void)ws_size;
  const float* x        = (const float*)d_in[0];
  const float* kernel   = (const float*)d_in[1];
  const float* w_reduce = (const float*)d_in[2];
  const float* b_reduce = (const float*)d_in[3];
  const float* w_g1     = (const float*)d_in[4];
  const float* b_g1     = (const float*)d_in[5];
  const float* w_g2     = (const float*)d_in[6];
  const float* b_g2     = (const float*)d_in[7];
  const float* w_g3     = (const float*)d_in[8];
  const float* b_g3     = (const float*)d_in[9];
  const float* w_g4     = (const float*)d_in[10];
  const float* b_g4     = (const float*)d_in[11];
  const float* w_expand = (const float*)d_in[12];
  const float* b_expand = (const float*)d_in[13];
  float* out = (float*)d_out;

  // ---- workspace layout (float offsets); all aliases time-disjoint ----
  float* ws_f = (float*)d_ws;
  float* cls   = ws_f;
  float* gA    = ws_f + 4194304;
  float* gB    = ws_f + 8323328;
  u16*  padsp  = (u16*)(ws_f + 4194304);
  u16*  T1e    = (u16*)(ws_f + 12452352);
  float* Gt    = ws_f;
  u16*  Ge     = (u16*)(ws_f + 12452352);
  u16*  E2     = (u16*)ws_f;
  u16*  Dh     = (u16*)(ws_f + 5242880);
  float2* tw   = (float2*)(ws_f + 28180992);
  float2* Kf2  = (float2*)(ws_f + 28182016);
  u16*  Wx1    = (u16*)(ws_f + 28540416);
  u16*  We     = (u16*)(ws_f + 28663296);
  u16*  B4t    = (u16*)(ws_f + 29072896);
  float* poolb = ws_f + 29154816;
  float* kpb   = ws_f + 29155392;
  float2* Rb   = (float2*)(ws_f + 29155968);

  // ---- static tables + R (single fused launch) ----
  tables_k<<<dim3(1600), 256, 0, stream>>>(tw, Wx1, We, B4t, kernel, Rb);

  // ---- reduce via MFMA ----
  reduce_mfma_k<<<dim3(1024), 256, 0, stream>>>(x, w_reduce, b_reduce, cls);
  // ---- conv chain via MFMA implicit GEMM ----
  conv3_mfma_k<<<dim3(254, NB), 256, 0, stream>>>(cls, w_g1, b_g1, gA, 256, 256, 1);
  conv3_mfma_k<<<dim3(252, NB), 256, 0, stream>>>(gA, w_g2, b_g2, gB, 254, 254, 1);
  conv3_mfma_k<<<dim3(250, NB), 256, 0, stream>>>(gB, w_g3, b_g3, gA, 252, 252, 0);
  pool_k<<<dim3(NB * 16 * 9), 256, 0, stream>>>(gA, poolb);
  kp_k<<<dim3(NB), 256, 0, stream>>>(poolb, w_g4, b_g4, kpb);

  // ---- pad + split, Kf (separable) ----
  padsplit_k<<<dim3(30720), 256, 0, stream>>>(cls, padsp);
  kf_k<<<dim3((298 * 150 + 255) / 256, NB), 256, 0, stream>>>(Rb, tw, Kf2);

  // ---- P1: T1e = Wx1 x pad^T  (M=320, MR=5; 384 blocks) ----
  gemmF<1, 5, 4><<<dim3(384), 256, 0, stream>>>(Wx1, padsp, nullptr, T1e, 3, 6, 5);
  // ---- P2: Gt = T1e x We^T  (M=160 exact, MR=5; 320 blocks) ----
  gemmF<2, 5, 4><<<dim3(320), 256, 0, stream>>>(T1e, We, Gt, nullptr, 5, 5, 10);
  // ---- Wiener + expand -> Ge ----
  gmul_k<<<dim3(240, IMGS), 256, 0, stream>>>(Gt, Kf2, kpb, tw, (u32*)Ge);
  // ---- P3: E = We(rows 2(m+21)) x Ge^T  (N=320 exact, NR=5; 256 blocks) ----
  gemmF<3, 4, 5><<<dim3(256), 256, 0, stream>>>(We, Ge, nullptr, E2, 2, 4, 10);
  // ---- P4: D = E2 x B4t^T -> Dh fp16 planes  (256 blocks) ----
  gemmF<4, 4, 4><<<dim3(256), 256, 0, stream>>>(E2, B4t, nullptr, Dh, 2, 4, 5);
  // ---- expand via MFMA ----
  expand_mfma_k<<<dim3(1024), 256, 0, stream>>>(Dh, w_expand, b_expand, out);
}

// Round 14
// 281.136 us; speedup vs baseline: 1.3522x; 1.0310x over previous
//
#include <hip/hip_runtime.h>
#include <math.h>

typedef unsigned short u16;
typedef unsigned int   u32;
typedef _Float16 f16x8 __attribute__((ext_vector_type(8)));
typedef __attribute__((ext_vector_type(4))) float f32x4;

#define NB    4
#define IMGS  64
#define DSLAB (256*256)
#define TWO_PI 6.283185307179586f

// Scale plan (pipeline linear in pad; total compensated exactly in P4):
#define S_WX1  0.015625f
#define S_GMUL 0.015625f
#define S_P3   0.0625f
#define S_P4   (65536.0f / 88804.0f)

// ---------- fp16 2-way split ----------
__device__ __forceinline__ void split2(float x, u16& h, u16& l) {
  _Float16 hh = (_Float16)x;
  float r = x - (float)hh;
  _Float16 ll = (_Float16)r;
  h = *(u16*)&hh; l = *(u16*)&ll;
}
__device__ __forceinline__ u16 f2h(float x) {
  _Float16 hh = (_Float16)x;
  return *(u16*)&hh;
}

// ---------- async global->LDS 16B DMA ----------
__device__ __forceinline__ void gload16(const u16* g, u16* l) {
  __builtin_amdgcn_global_load_lds(
      (__attribute__((address_space(1))) void*)(g),
      (__attribute__((address_space(3))) void*)(l),
      16, 0, 0);
}

// ---------- fused static tables + kernel-DFT row factor R ----------
__global__ __launch_bounds__(256) void tables_k(float2* __restrict__ tw,
                                                u16* __restrict__ Wx1,
                                                u16* __restrict__ We,
                                                u16* __restrict__ B4t,
                                                const float* __restrict__ ker,
                                                float2* __restrict__ Rb) {
  int idx = blockIdx.x * 256 + threadIdx.x;
  if (idx < 298) {
    float ang = (-TWO_PI / 298.0f) * (float)idx;
    float s, c; sincosf(ang, &s, &c);
    tw[idx] = make_float2(c, s);
  }
  if (idx < 12600) {   // R[b][i][v]
    int b = idx / 3150, rem = idx % 3150;
    int i = rem / 150, v = rem % 150;
    int tt = (2980 - 10 * v) % 298;
    float rr = 0.f, ri = 0.f;
#pragma unroll
    for (int j = 0; j < 21; ++j) {
      float ang = (-TWO_PI / 298.0f) * (float)tt;
      float sn, cs; sincosf(ang, &sn, &cs);
      float kv = ker[b * 441 + i * 21 + j];
      rr = fmaf(kv, cs, rr); ri = fmaf(kv, sn, ri);
      tt += v; if (tt >= 298) tt -= 298;
    }
    Rb[idx] = make_float2(rr, ri);
  }
  if (idx < 122880) {   // Wx1 [2][384][320]
    int rho = idx / 320, n = idx % 320;
    float val = 0.f;
    if (rho < 300 && n < 298) {
      int v = rho >> 1, s = rho & 1;
      int m = (v * n) % 298;
      float ph = (TWO_PI / 298.0f) * (float)m;
      float sn, cs; sincosf(ph, &sn, &cs);
      val = (s ? sn : cs) * S_WX1;
    }
    u16 h, l; split2(val, h, l);
    Wx1[idx] = h; Wx1[122880 + idx] = l;
  }
  if (idx < 409600) {   // We [2][640][640]
    int j2 = idx / 640, k = idx % 640;
    int u = j2 >> 1, pc = j2 & 1;
    int mm = k >> 1, p = k & 1;
    float val = 0.f;
    if (u < 298 && mm < 298) {
      int m = (u * mm) % 298;
      float ph = (TWO_PI / 298.0f) * (float)m;
      float sn, cs; sincosf(ph, &sn, &cs);
      val = (pc == 0) ? (p == 0 ? cs : -sn) : (p == 0 ? -sn : -cs);
    }
    u16 h, l; split2(val, h, l);
    We[idx] = h; We[409600 + idx] = l;
  }
  if (idx < 40960) {    // B4t [1][256][320]
    int v = idx / 256, n = idx % 256;
    float re = 0.f, im = 0.f;
    if (v < 150) {
      int m = (v * (n + 21)) % 298;
      float ang = (-TWO_PI / 298.0f) * (float)m;
      float s, c; sincosf(ang, &s, &c);
      float fac = (v >= 1 && v < 149) ? 2.f : 1.f;
      re = fac * c; im = fac * s;
    }
    size_t o = (size_t)n * 320 + 2 * v;
    B4t[o] = f2h(re); B4t[o + 1] = f2h(im);
  }
}

// ---------- 1x1 reduce conv via MFMA ----------
__global__ __launch_bounds__(256) void reduce_mfma_k(const float* __restrict__ x,
                                                     const float* __restrict__ w,
                                                     const float* __restrict__ bias,
                                                     float* __restrict__ cls) {
  __shared__ u16 Wp[2 * 1024];
  __shared__ float bs[16];
  int t = threadIdx.x;
  for (int i = t; i < 1024; i += 256) {
    u16 h, l; split2(w[i], h, l);
    Wp[i] = h; Wp[1024 + i] = l;
  }
  if (t < 16) bs[t] = bias[t];
  __syncthreads();
  const int b = blockIdx.x >> 8;
  const int px0 = (blockIdx.x & 255) * 256;
  const int l = t & 63, wv = t >> 6;
  const int pxb = px0 + wv * 64;
  const int kgrp = l >> 4;
  f16x8 af[2][2];
#pragma unroll
  for (int kt = 0; kt < 2; ++kt)
#pragma unroll
    for (int p = 0; p < 2; ++p)
      af[kt][p] = *(const f16x8*)&Wp[p * 1024 + (l & 15) * 64 + kt * 32 + kgrp * 8];
  const float* xb = x + (size_t)b * 64 * 65536;
  float xv[2][4][8];
#pragma unroll
  for (int kt = 0; kt < 2; ++kt)
#pragma unroll
    for (int pxf = 0; pxf < 4; ++pxf) {
      int px = pxb + pxf * 16 + (l & 15);
      const float* p0 = xb + (size_t)(kt * 32 + kgrp * 8) * 65536 + px;
#pragma unroll
      for (int j = 0; j < 8; ++j) xv[kt][pxf][j] = p0[(size_t)j * 65536];
    }
  f32x4 acc[4];
#pragma unroll
  for (int i = 0; i < 4; ++i) acc[i] = (f32x4){0.f, 0.f, 0.f, 0.f};
#pragma unroll
  for (int kt = 0; kt < 2; ++kt)
#pragma unroll
    for (int pxf = 0; pxf < 4; ++pxf) {
      f16x8 bh, bl;
#pragma unroll
      for (int j = 0; j < 8; ++j) {
        float v = xv[kt][pxf][j];
        _Float16 hh = (_Float16)v;
        _Float16 ll = (_Float16)(v - (float)hh);
        bh[j] = hh; bl[j] = ll;
      }
      f32x4 a = acc[pxf];
      a = __builtin_amdgcn_mfma_f32_16x16x32_f16(af[kt][0], bl, a, 0, 0, 0);
      a = __builtin_amdgcn_mfma_f32_16x16x32_f16(af[kt][1], bh, a, 0, 0, 0);
      a = __builtin_amdgcn_mfma_f32_16x16x32_f16(af[kt][0], bh, a, 0, 0, 0);
      acc[pxf] = a;
    }
  float* ob = cls + (size_t)b * 16 * 65536;
#pragma unroll
  for (int pxf = 0; pxf < 4; ++pxf) {
    int px = pxb + pxf * 16 + (l & 15);
#pragma unroll
    for (int i = 0; i < 4; ++i) {
      int oc = kgrp * 4 + i;
      ob[(size_t)oc * 65536 + px] = acc[pxf][i] + bs[oc];
    }
  }
}

// ---------- 1x1 expand conv via MFMA ----------
__global__ __launch_bounds__(256) void expand_mfma_k(const u16* __restrict__ Dh,
                                                     const float* __restrict__ w,
                                                     const float* __restrict__ bias,
                                                     float* __restrict__ out) {
  __shared__ u16 Wp[2 * 2048];
  __shared__ float bs[64];
  int t = threadIdx.x;
  for (int i = t; i < 2048; i += 256) {
    int oc = i >> 5, k = i & 31;
    float v = (k < 16) ? w[oc * 16 + k] : 0.f;
    u16 h, l; split2(v, h, l);
    Wp[i] = h; Wp[2048 + i] = l;
  }
  if (t < 64) bs[t] = bias[t];
  __syncthreads();
  const int b = blockIdx.x >> 8;
  const int px0 = (blockIdx.x & 255) * 256;
  const int l = t & 63, wv = t >> 6;
  const int pxb = px0 + wv * 64;
  const int kgrp = l >> 4;
  f16x8 af[4][2];
#pragma unroll
  for (int mf = 0; mf < 4; ++mf)
#pragma unroll
    for (int p = 0; p < 2; ++p)
      af[mf][p] = *(const f16x8*)&Wp[p * 2048 + (mf * 16 + (l & 15)) * 32 + kgrp * 8];
  const int chb = kgrp * 8;
  f32x4 acc[4][4];
#pragma unroll
  for (int i = 0; i < 4; ++i)
#pragma unroll
    for (int j = 0; j < 4; ++j) acc[i][j] = (f32x4){0.f, 0.f, 0.f, 0.f};
#pragma unroll
  for (int pxf = 0; pxf < 4; ++pxf) {
    int px = pxb + pxf * 16 + (l & 15);
    f16x8 bh, bl;
#pragma unroll
    for (int j = 0; j < 8; ++j) {
      _Float16 hv = (_Float16)0.f, lv = (_Float16)0.f;
      if (chb < 16) {
        size_t off = (size_t)(b * 16 + chb + j) * 65536 + px;
        hv = *(const _Float16*)&Dh[off];
        lv = *(const _Float16*)&Dh[4194304u + off];
      }
      bh[j] = hv; bl[j] = lv;
    }
#pragma unroll
    for (int mf = 0; mf < 4; ++mf) {
      f32x4 a = acc[pxf][mf];
      a = __builtin_amdgcn_mfma_f32_16x16x32_f16(af[mf][0], bl, a, 0, 0, 0);
      a = __builtin_amdgcn_mfma_f32_16x16x32_f16(af[mf][1], bh, a, 0, 0, 0);
      a = __builtin_amdgcn_mfma_f32_16x16x32_f16(af[mf][0], bh, a, 0, 0, 0);
      acc[pxf][mf] = a;
    }
  }
  float* ob = out + (size_t)b * 64 * 65536;
#pragma unroll
  for (int pxf = 0; pxf < 4; ++pxf) {
    int px = pxb + pxf * 16 + (l & 15);
#pragma unroll
    for (int mf = 0; mf < 4; ++mf)
#pragma unroll
      for (int i = 0; i < 4; ++i) {
        int oc = mf * 16 + kgrp * 4 + i;
        ob[(size_t)oc * 65536 + px] = acc[pxf][mf][i] + bs[oc];
      }
  }
}

// ---------- 3x3 VALID conv via MFMA (implicit GEMM) ----------
__global__ __launch_bounds__(256) void conv3_mfma_k(const float* __restrict__ in,
                                                    const float* __restrict__ w,
                                                    const float* __restrict__ bias,
                                                    float* __restrict__ out,
                                                    int HI, int WI, int relu) {
  __shared__ u16 Wp[2 * 2560];
  __shared__ float bs[16];
  int t = threadIdx.x;
  for (int i = t; i < 2560; i += 256) {
    int oc = i / 160, k = i % 160;
    int dydx = k >> 4, ci = k & 15;
    float v = (dydx < 9) ? w[oc * 144 + ci * 9 + dydx] : 0.f;
    u16 h, l; split2(v, h, l);
    Wp[i] = h; Wp[2560 + i] = l;
  }
  if (t < 16) bs[t] = bias[t];
  __syncthreads();
  const int HO = HI - 2, WO = WI - 2;
  const int y = blockIdx.x;
  const int b = blockIdx.y;
  const int l = t & 63, wv = t >> 6;
  const int pxcol = l & 15, kgrp = l >> 4;
  const int plane = HI * WI;

  f16x8 af[5][2];
#pragma unroll
  for (int kt = 0; kt < 5; ++kt)
#pragma unroll
    for (int p = 0; p < 2; ++p)
      af[kt][p] = *(const f16x8*)&Wp[p * 2560 + (l & 15) * 160 + kt * 32 + kgrp * 8];

  int dyA[5], dxA[5], okA[5];
#pragma unroll
  for (int kt = 0; kt < 5; ++kt) {
    int dydx = kt * 2 + (kgrp >> 1);
    okA[kt] = (dydx < 9);
    int dd = okA[kt] ? dydx : 0;
    dyA[kt] = dd / 3; dxA[kt] = dd % 3;
  }
  const int ci0 = (kgrp & 1) * 8;
  const float* ib = in + (size_t)b * 16 * plane + (size_t)ci0 * plane;
  float* ob = out + (size_t)b * 16 * (HO * WO) + (size_t)y * WO;

#pragma unroll
  for (int it = 0; it < 4; ++it) {
    const int x = wv * 64 + it * 16 + pxcol;
    f32x4 acc = (f32x4){0.f, 0.f, 0.f, 0.f};
#pragma unroll
    for (int kt = 0; kt < 5; ++kt) {
      f16x8 bh, bl;
      if (okA[kt]) {
        const float* p0 = ib + (size_t)(y + dyA[kt]) * WI + x + dxA[kt];
#pragma unroll
        for (int j = 0; j < 8; ++j) {
          float v = p0[(size_t)j * plane];
          _Float16 hh = (_Float16)v;
          bh[j] = hh; bl[j] = (_Float16)(v - (float)hh);
        }
      } else {
#pragma unroll
        for (int j = 0; j < 8; ++j) { bh[j] = (_Float16)0.f; bl[j] = (_Float16)0.f; }
      }
      acc = __builtin_amdgcn_mfma_f32_16x16x32_f16(af[kt][0], bl, acc, 0, 0, 0);
      acc = __builtin_amdgcn_mfma_f32_16x16x32_f16(af[kt][1], bh, acc, 0, 0, 0);
      acc = __builtin_amdgcn_mfma_f32_16x16x32_f16(af[kt][0], bh, acc, 0, 0, 0);
    }
    if (x < WO) {
#pragma unroll
      for (int i = 0; i < 4; ++i) {
        int oc = kgrp * 4 + i;
        float v = acc[i] + bs[oc];
        if (relu) v = v > 0.f ? v : 0.1f * v;
        ob[(size_t)oc * (HO * WO) + x] = v;
      }
    }
  }
}

// ---------- adaptive avg pool 250x250 -> 3x3 ----------
__global__ __launch_bounds__(256) void pool_k(const float* __restrict__ g,
                                              float* __restrict__ poolo) {
  int blk = blockIdx.x;
  int bc = blk / 9;
  int ij = blk % 9;
  int i = ij / 3, j = ij % 3;
  const int r0s[3] = {0, 83, 166}, r1s[3] = {84, 167, 250};
  int r0 = r0s[i], r1 = r1s[i], c0 = r0s[j], c1 = r1s[j];
  const float* p = g + (size_t)bc * 62500;
  int nc = c1 - c0;
  int tot = (r1 - r0) * nc;
  float s = 0.f;
  for (int e = threadIdx.x; e < tot; e += 256) {
    int rr = e / nc, cc = e % nc;
    s += p[(r0 + rr) * 250 + c0 + cc];
  }
  for (int off = 32; off > 0; off >>= 1) s += __shfl_down(s, off, 64);
  __shared__ float red[4];
  int lane = threadIdx.x & 63, wid = threadIdx.x >> 6;
  if (lane == 0) red[wid] = s;
  __syncthreads();
  if (threadIdx.x == 0) poolo[blk] = (red[0] + red[1] + red[2] + red[3]) / (float)tot;
}

// ---------- kernel_P ----------
__global__ __launch_bounds__(256) void kp_k(const float* __restrict__ poolv,
                                            const float* __restrict__ w4,
                                            const float* __restrict__ b4,
                                            float* __restrict__ kp) {
  int b = blockIdx.x;
  int t = threadIdx.x;
  __shared__ float vals[144];
  __shared__ float w_[256];
  __shared__ float bb[16];
  if (t < 256) w_[t] = w4[t];
  if (t < 16) bb[t] = b4[t];
  __syncthreads();
  if (t < 144) {
    int c = t / 9, ij = t % 9;
    float a = bb[c];
    for (int k = 0; k < 16; k++)
      a = fmaf(w_[c * 16 + k], poolv[b * 144 + k * 9 + ij], a);
    vals[t] = expf(a);
  }
  __syncthreads();
  if (t < 144) {
    int c = t / 9;
    float m = 0.f;
#pragma unroll
    for (int q = 0; q < 9; q++) m += vals[c * 9 + q];
    kp[b * 144 + t] = vals[t] - m * (1.0f / 9.0f);
  }
}

// ---------- pad (edge) + split2 into [2][64][384][320] fp16 ----------
__global__ __launch_bounds__(256) void padsplit_k(const float* __restrict__ cls,
                                                  u16* __restrict__ p0) {
  size_t idx = (size_t)blockIdx.x * 256 + threadIdx.x;
  if (idx >= 7864320u) return;
  int n = (int)(idx % 320);
  size_t rest = idx / 320;
  int m = (int)(rest % 384);
  size_t img = rest / 384;
  float val = 0.f;
  if (m < 298 && n < 298) {
    int sy = min(max(m - 21, 0), 255);
    int sx = min(max(n - 21, 0), 255);
    val = cls[img * 65536 + (size_t)sy * 256 + sx];
  }
  u16 h, l; split2(val, h, l);
  p0[idx] = h;
  p0[7864320u + idx] = l;
}

// ---------- Kf via separable factor ----------
__global__ __launch_bounds__(256) void kf_k(const float2* __restrict__ Rb,
                                            const float2* __restrict__ tw,
                                            float2* __restrict__ Kf) {
  int b = blockIdx.y;
  int uv = blockIdx.x * 256 + threadIdx.x;
  if (uv >= 298 * 150) return;
  int u = uv / 150, v = uv % 150;
  int tt = (2980 - 10 * u) % 298;
  const float2* Rp = Rb + b * 3150 + v;
  float ar = 0.f, ai = 0.f;
#pragma unroll
  for (int i = 0; i < 21; ++i) {
    float2 wv = tw[tt];
    float2 r = Rp[i * 150];
    ar += wv.x * r.x - wv.y * r.y;
    ai += wv.x * r.y + wv.y * r.x;
    tt += u; if (tt >= 298) tt -= 298;
  }
  Kf[(size_t)b * 44700 + uv] = make_float2(ar, ai);
}

// ---------- Wiener on Gt[v][u] fp32 -> Ge [1][64][384][640] fp16 expanded ----
__global__ __launch_bounds__(256) void gmul_k(const float* __restrict__ Gt,
                                              const float2* __restrict__ Kf,
                                              const float* __restrict__ kp,
                                              const float2* __restrict__ tw,
                                              u32* __restrict__ Geu) {
  int img = blockIdx.y;
  int b = img >> 4;
  __shared__ float kps[9];
  if (threadIdx.x < 9) kps[threadIdx.x] = kp[img * 9 + threadIdx.x];
  __syncthreads();
  int idx = blockIdx.x * 256 + threadIdx.x;
  if (idx >= 192 * 320) return;
  int u = idx % 320, v = idx / 320;
  float gr = 0.f, gi = 0.f;
  if (v < 150 && u < 298) {
    const float* gp = Gt + (size_t)img * 102400 + (size_t)v * 640 + 2 * u;
    float fr = gp[0], fi = gp[1];
    int um = (u == 0) ? 0 : (298 - u);
    int vm = (v == 0) ? 0 : (298 - v);
    int iu[3] = {um, 0, u}, jv[3] = {vm, 0, v};
    float pr = 0.f, pi = 0.f;
#pragma unroll
    for (int i = 0; i < 3; i++) {
#pragma unroll
      for (int j = 0; j < 3; j++) {
        int tt = iu[i] + jv[j];
        if (tt >= 298) tt -= 298;
        float kv = kps[i * 3 + j];
        float2 wv = tw[tt];
        pr = fmaf(kv, wv.x, pr);
        pi = fmaf(kv, wv.y, pi);
      }
    }
    float2 kf = Kf[(size_t)b * 44700 + (size_t)u * 150 + v];
    float denom = kf.x * kf.x + kf.y * kf.y + pr * pr + pi * pi;
    float inv = 1.0f / denom;
    float ir = kf.x * inv, ii = -kf.y * inv;
    gr = (ir * fr - ii * fi) * S_GMUL;
    gi = (ir * fi + ii * fr) * S_GMUL;
  }
  u16 ghr = f2h(gr), ghi = f2h(gi);
  size_t base = (size_t)img * 122880 + (size_t)(2 * v) * 320 + u;
  Geu[base]       = (u32)ghr | ((u32)ghi << 16);
  Geu[base + 320] = (u32)ghi | ((u32)(ghr ^ 0x8000u) << 16);
}

// ---------- staging helper, BK=32 (64B rows, 16 rows per wave-issue) --------
// LDS slot s of row r holds global chunk s ^ ((r>>1)&3); dest stays linear.
template <int V, int PL, int MR, int NR>
__device__ __forceinline__ void stageT(const u16* __restrict__ Asrc,
                                       const u16* __restrict__ Bsrc,
                                       u16* Lb, int img, int m0, int n0,
                                       int kt, int w, int l) {
  const int kb = kt * 32;
  const int rl = l >> 2;                       // row within 16-row block
  const int sub = (l & 3) ^ ((l >> 3) & 3);    // pre-swizzled global chunk
  constexpr int TA = 2 * PL * MR;
  constexpr int TB = 2 * PL * NR;
  constexpr int T = TA + TB;
  constexpr int TP = (T + 3) & ~3;
#pragma unroll
  for (int i = 0; i < TP / 4; ++i) {
    int q0 = w + i * 4;
    int q = (q0 < T) ? q0 : q0 - 4;            // benign same-wave re-issue pad
    const u16* src;
    if (q < TA) {
      int p = q / (2 * MR);
      int j = q % (2 * MR);
      int r = m0 + j * 16 + rl;
      if constexpr (V == 1) {
        src = Asrc + (size_t)p * 122880u + (size_t)r * 320 + kb + sub * 8;
      } else if constexpr (V == 2) {
        src = Asrc + (size_t)p * 7864320u + (size_t)img * 122880u +
              (size_t)r * 640 + kb + sub * 8;
      } else if constexpr (V == 3) {
        src = Asrc + (size_t)(2 * (r + 21)) * 640 + kb + sub * 8;
      } else {
        src = Asrc + (size_t)img * 81920u + (size_t)r * 320 + kb + sub * 8;
      }
    } else {
      int qb = q - TA;
      int p = qb / (2 * NR);
      int j = qb % (2 * NR);
      int rr = n0 + j * 16 + rl;
      if constexpr (V == 1) {
        src = Bsrc + (size_t)p * 7864320u + (size_t)img * 122880u +
              (size_t)rr * 320 + kb + sub * 8;
      } else if constexpr (V == 2) {
        src = Bsrc + (size_t)p * 409600u + (size_t)rr * 640 + kb + sub * 8;
      } else if constexpr (V == 3) {
        src = Bsrc + (size_t)img * 245760u + (size_t)rr * 640 + kb + sub * 8;
      } else {
        src = Bsrc + (size_t)rr * 320 + kb + sub * 8;
      }
    }
    gload16(src, Lb + q * 512 + l * 8);
  }
}

// ---------- fp16-split MFMA GEMM: BK=32 dbuf + counted vmcnt + XCD swizzle --
// Block tile (32*MR) x (32*NR); 4 waves (2x2); LDS per buf halved vs BK=64.
template <int V, int MR, int NR>
__global__ __launch_bounds__(256) void gemmF(
    const u16* __restrict__ Asrc, const u16* __restrict__ Bsrc,
    float* __restrict__ oF, u16* __restrict__ o0,
    int nbn, int npi, int KT) {
  constexpr int PL = (V <= 2) ? 2 : 1;
  constexpr int ASZ = PL * 32 * MR * 32;   // u16
  constexpr int BSZ = PL * 32 * NR * 32;
  constexpr int BUF = ASZ + BSZ;
  constexpr int LD = (((2 * PL * (MR + NR)) + 3) & ~3) / 4;  // loads/thread/stage
  __shared__ u16 lds[2 * BUF];
  const int tid = threadIdx.x;
  const int nwg = gridDim.x;
  const int wg = blockIdx.x;
  const int vid = (wg & 7) * (nwg >> 3) + (wg >> 3);
  const int img = vid / npi;
  const int rem = vid % npi;
  const int m0 = (rem / nbn) * (32 * MR);
  const int n0 = (rem % nbn) * (32 * NR);
  const int l = tid & 63;
  const int w = tid >> 6;
  const int wm = w & 1, wn = w >> 1;
  const int arow = wm * (16 * MR) + (l & 15);
  const int brow = wn * (16 * NR) + (l & 15);
  const int c8 = ((l >> 4) ^ ((l >> 1) & 3)) * 8;   // swizzled read slot

  f32x4 acc[MR][NR];
#pragma unroll
  for (int i = 0; i < MR; i++)
#pragma unroll
    for (int j = 0; j < NR; j++) acc[i][j] = (f32x4){0.f, 0.f, 0.f, 0.f};

  stageT<V, PL, MR, NR>(Asrc, Bsrc, lds, img, m0, n0, 0, w, l);
  int c = 0;
  for (int kt = 0; kt < KT; ++kt) {
    if (kt + 1 < KT) {
      stageT<V, PL, MR, NR>(Asrc, Bsrc, lds + (c ^ 1) * BUF, img, m0, n0, kt + 1, w, l);
      asm volatile("s_waitcnt vmcnt(%0)" :: "n"(LD) : "memory");
    } else {
      asm volatile("s_waitcnt vmcnt(0)" ::: "memory");
    }
    __builtin_amdgcn_s_barrier();
    const u16* Al = lds + c * BUF;
    const u16* Bl = Al + ASZ;
    f16x8 af[MR][PL], bf[NR][PL];
#pragma unroll
    for (int fm = 0; fm < MR; ++fm)
#pragma unroll
      for (int p = 0; p < PL; ++p)
        af[fm][p] = *(const f16x8*)&Al[p * (32 * MR * 32) + (arow + fm * 16) * 32 + c8];
#pragma unroll
    for (int fn = 0; fn < NR; ++fn)
#pragma unroll
      for (int p = 0; p < PL; ++p)
        bf[fn][p] = *(const f16x8*)&Bl[p * (32 * NR * 32) + (brow + fn * 16) * 32 + c8];
#pragma unroll
    for (int fm = 0; fm < MR; ++fm)
#pragma unroll
      for (int fn = 0; fn < NR; ++fn) {
        f32x4 a = acc[fm][fn];
        if constexpr (PL == 2) {
          a = __builtin_amdgcn_mfma_f32_16x16x32_f16(af[fm][1], bf[fn][0], a, 0, 0, 0);
          a = __builtin_amdgcn_mfma_f32_16x16x32_f16(af[fm][0], bf[fn][1], a, 0, 0, 0);
          a = __builtin_amdgcn_mfma_f32_16x16x32_f16(af[fm][0], bf[fn][0], a, 0, 0, 0);
        } else {
          a = __builtin_amdgcn_mfma_f32_16x16x32_f16(af[fm][0], bf[fn][0], a, 0, 0, 0);
        }
        acc[fm][fn] = a;
      }
    asm volatile("" ::: "memory");
    __builtin_amdgcn_s_barrier();
    c ^= 1;
  }

  // ---- epilogue ----
  const int rowL = (l >> 4) * 4;
  const int colL = l & 15;
#pragma unroll
  for (int fm = 0; fm < MR; ++fm)
#pragma unroll
    for (int fn = 0; fn < NR; ++fn) {
      int gcol = n0 + wn * (16 * NR) + fn * 16 + colL;
      int rbase = m0 + wm * (16 * MR) + fm * 16 + rowL;
      if constexpr (V == 1) {
        if (gcol < 320) {
          u32* T1u = (u32*)o0;
#pragma unroll
          for (int i = 0; i < 4; i += 2) {
            int rho = rbase + i;
            int v = rho >> 1;
            u16 h0, l0, h1, l1;
            split2(acc[fm][fn][i], h0, l0);
            split2(acc[fm][fn][i + 1], h1, l1);
            size_t off = (size_t)img * 61440u + (size_t)v * 320 + gcol;
            T1u[off] = (u32)h0 | ((u32)h1 << 16);
            T1u[3932160u + off] = (u32)l0 | ((u32)l1 << 16);
          }
        }
      } else if constexpr (V == 2) {
#pragma unroll
        for (int i = 0; i < 4; ++i) {
          int vg = rbase + i;
          if (vg < 160)
            oF[(size_t)img * 102400u + (size_t)vg * 640 + gcol] = acc[fm][fn][i];
        }
      } else if constexpr (V == 3) {
        if (gcol < 320) {
#pragma unroll
          for (int i = 0; i < 4; ++i) {
            int mg = rbase + i;
            size_t off = (size_t)img * 81920u + (size_t)mg * 320 + gcol;
            o0[off] = f2h(acc[fm][fn][i] * S_P3);
          }
        }
      } else {
#pragma unroll
        for (int i = 0; i < 4; ++i) {
          int mg = rbase + i;
          u16 h, lo;
          split2(acc[fm][fn][i] * S_P4, h, lo);
          size_t off = (size_t)img * 65536u + (size_t)mg * 256 + gcol;
          o0[off] = h;
          o0[4194304u + off] = lo;
        }
      }
    }
}

extern "C" void kernel_launch(void* const* d_in, const int* in_sizes, int n_in,
                              void* d_out, int out_size, void* d_ws, size_t ws_size,
                              hipStream_t stream) {
  (void)in_sizes; (void)n_in; (void)out_size; (void)ws_size;
  const float* x        = (const float*)d_in[0];
  const float* kernel   = (const float*)d_in[1];
  const float* w_reduce = (const float*)d_in[2];
  const float* b_reduce = (const float*)d_in[3];
  const float* w_g1     = (const float*)d_in[4];
  const float* b_g1     = (const float*)d_in[5];
  const float* w_g2     = (const float*)d_in[6];
  const float* b_g2     = (const float*)d_in[7];
  const float* w_g3     = (const float*)d_in[8];
  const float* b_g3     = (const float*)d_in[9];
  const float* w_g4     = (const float*)d_in[10];
  const float* b_g4     = (const float*)d_in[11];
  const float* w_expand = (const float*)d_in[12];
  const float* b_expand = (const float*)d_in[13];
  float* out = (float*)d_out;

  // ---- workspace layout (float offsets); all aliases time-disjoint ----
  float* ws_f = (float*)d_ws;
  float* cls   = ws_f;
  float* gA    = ws_f + 4194304;
  float* gB    = ws_f + 8323328;
  u16*  padsp  = (u16*)(ws_f + 4194304);
  u16*  T1e    = (u16*)(ws_f + 12452352);
  float* Gt    = ws_f;
  u16*  Ge     = (u16*)(ws_f + 12452352);
  u16*  E2     = (u16*)ws_f;
  u16*  Dh     = (u16*)(ws_f + 5242880);
  float2* tw   = (float2*)(ws_f + 28180992);
  float2* Kf2  = (float2*)(ws_f + 28182016);
  u16*  Wx1    = (u16*)(ws_f + 28540416);
  u16*  We     = (u16*)(ws_f + 28663296);
  u16*  B4t    = (u16*)(ws_f + 29072896);
  float* poolb = ws_f + 29154816;
  float* kpb   = ws_f + 29155392;
  float2* Rb   = (float2*)(ws_f + 29155968);

  // ---- static tables + R (single fused launch) ----
  tables_k<<<dim3(1600), 256, 0, stream>>>(tw, Wx1, We, B4t, kernel, Rb);

  // ---- reduce via MFMA ----
  reduce_mfma_k<<<dim3(1024), 256, 0, stream>>>(x, w_reduce, b_reduce, cls);
  // ---- conv chain via MFMA implicit GEMM ----
  conv3_mfma_k<<<dim3(254, NB), 256, 0, stream>>>(cls, w_g1, b_g1, gA, 256, 256, 1);
  conv3_mfma_k<<<dim3(252, NB), 256, 0, stream>>>(gA, w_g2, b_g2, gB, 254, 254, 1);
  conv3_mfma_k<<<dim3(250, NB), 256, 0, stream>>>(gB, w_g3, b_g3, gA, 252, 252, 0);
  pool_k<<<dim3(NB * 16 * 9), 256, 0, stream>>>(gA, poolb);
  kp_k<<<dim3(NB), 256, 0, stream>>>(poolb, w_g4, b_g4, kpb);

  // ---- pad + split, Kf (separable) ----
  padsplit_k<<<dim3(30720), 256, 0, stream>>>(cls, padsp);
  kf_k<<<dim3((298 * 150 + 255) / 256, NB), 256, 0, stream>>>(Rb, tw, Kf2);

  // ---- P1: T1e = Wx1 x pad^T  (M=320, MR=5; KT=10) ----
  gemmF<1, 5, 4><<<dim3(384), 256, 0, stream>>>(Wx1, padsp, nullptr, T1e, 3, 6, 10);
  // ---- P2: Gt = T1e x We^T  (M=160 exact, MR=5; KT=20) ----
  gemmF<2, 5, 4><<<dim3(320), 256, 0, stream>>>(T1e, We, Gt, nullptr, 5, 5, 20);
  // ---- Wiener + expand -> Ge ----
  gmul_k<<<dim3(240, IMGS), 256, 0, stream>>>(Gt, Kf2, kpb, tw, (u32*)Ge);
  // ---- P3: E = We(rows 2(m+21)) x Ge^T  (N=320 exact, NR=5; KT=20) ----
  gemmF<3, 4, 5><<<dim3(256), 256, 0, stream>>>(We, Ge, nullptr, E2, 2, 4, 20);
  // ---- P4: D = E2 x B4t^T -> Dh fp16 planes  (KT=10) ----
  gemmF<4, 4, 4><<<dim3(256), 256, 0, stream>>>(E2, B4t, nullptr, Dh, 2, 4, 10);
  // ---- expand via MFMA ----
  expand_mfma_k<<<dim3(1024), 256, 0, stream>>>(Dh, w_expand, b_expand, out);
}